// Round 9
// baseline (300.937 us; speedup 1.0000x reference)
//
#include <hip/hip_runtime.h>
#include <math.h>

// R10 (291us): agg2out 62us — WRITE fix worked (40->1.2MB) but array-indexed
// u[8]/sc[8] batches let the compiler serialize gathers (VGPR 40, ~19us/wave
// = 8 loads x ~900ns serial). agg1's named-scalar 4-deep runs at 6.7 TB/s
// effective (49us = 327MB bandwidth plateau; left alone).
// R11: agg2out rebuilt in agg1's exact shape: 1 node / 64-lane wave, 4B/lane
// (2 bf16 feats), named u0..u3 + as0..as3 4-deep unroll + tail; fused
// pooling + W_out epilogue kept (2 atomics/node).

#define NEG_SLOPE 0.2f
#define LDSB 40

using bf16x8 = __attribute__((ext_vector_type(8))) __bf16;
using f32x4  = __attribute__((ext_vector_type(4))) float;

// ---------- bf16 helpers (storage ushort, fp32 compute) ----------
__device__ __forceinline__ ushort f2bf(float f) {
    unsigned u = __float_as_uint(f);
    unsigned r = (u + 0x7FFFu + ((u >> 16) & 1u)) >> 16;   // RNE
    return (ushort)r;
}
__device__ __forceinline__ unsigned pack2(float a, float b) {
    return (unsigned)f2bf(a) | ((unsigned)f2bf(b) << 16);
}
__device__ __forceinline__ float bflo(unsigned u) { return __uint_as_float(u << 16); }
__device__ __forceinline__ float bfhi(unsigned u) { return __uint_as_float(u & 0xFFFF0000u); }
__device__ __forceinline__ void unpack8(uint4 u, float* f) {
    f[0] = bflo(u.x); f[1] = bfhi(u.x);
    f[2] = bflo(u.y); f[3] = bfhi(u.y);
    f[4] = bflo(u.z); f[5] = bfhi(u.z);
    f[6] = bflo(u.w); f[7] = bfhi(u.w);
}

// ---------------- prep: bf16 converts (blocks [0,cvtBlocks)) + edge count ----
__global__ __launch_bounds__(256) void prep(const float* __restrict__ x, ushort* __restrict__ xb, int nx4,
                                            const float* __restrict__ w1, ushort* __restrict__ w1b, int nw14,
                                            const float* __restrict__ w2, ushort* __restrict__ w2b, int nw24,
                                            int cvtBlocks,
                                            const int* __restrict__ edst, int* __restrict__ cnt, int E) {
    int blk = blockIdx.x;
    if (blk < cvtBlocks) {
        int j = blk * 256 + threadIdx.x;
        const float* src; ushort* dst;
        if (j < nx4) { src = x; dst = xb; }
        else {
            j -= nx4;
            if (j < nw14) { src = w1; dst = w1b; }
            else {
                j -= nw14;
                if (j >= nw24) return;
                src = w2; dst = w2b;
            }
        }
        float4 v = ((const float4*)src)[j];
        uint2 o;
        o.x = pack2(v.x, v.y);
        o.y = pack2(v.z, v.w);
        ((uint2*)dst)[j] = o;
    } else {
        int e = (blk - cvtBlocks) * 256 + threadIdx.x;
        if (e < E) atomicAdd(&cnt[edst[e]], 1);
    }
}

// ---------------- GEMM body: C[M,N]=A[M,K]*B[N,K]^T, software-pipelined ------
__device__ __forceinline__ void gemm_body(ushort* As, ushort* Bs,
                                          const ushort* __restrict__ A,
                                          const ushort* __restrict__ B,
                                          ushort* __restrict__ C,
                                          int M, int N, int K, int bx, int by,
                                          const float* __restrict__ att_s,
                                          const float* __restrict__ att_d,
                                          float* __restrict__ sout,
                                          float* __restrict__ dout, int H) {
    int t = threadIdx.x;
    int wave = t >> 6, lane = t & 63;
    int quad = lane >> 4, l16 = lane & 15;
    int m0 = bx * 128, n0 = by * 128;
    int wm = (wave & 1) * 64;
    int wn = (wave >> 1) * 64;
    int srow = t >> 1;
    int sseg = (t & 1) * 16;          // element offset (16 bf16 = 32 B)
    int growA = m0 + srow;
    bool okA = growA < M;
    f32x4 acc[4][4] = {};             // [mi][nj]
    uint4 av0, av1, bv0, bv1;
    {   // preload chunk 0
        if (okA) {
            const uint4* gp = (const uint4*)(A + (size_t)growA * K + sseg);
            av0 = gp[0]; av1 = gp[1];
        } else { av0 = make_uint4(0, 0, 0, 0); av1 = av0; }
        const uint4* gq = (const uint4*)(B + (size_t)(n0 + srow) * K + sseg);
        bv0 = gq[0]; bv1 = gq[1];
    }
    for (int k0 = 0; k0 < K; k0 += 32) {
        __syncthreads();   // previous chunk's LDS readers done
        *(uint4*)&As[srow * LDSB + sseg]     = av0;
        *(uint4*)&As[srow * LDSB + sseg + 8] = av1;
        *(uint4*)&Bs[srow * LDSB + sseg]     = bv0;
        *(uint4*)&Bs[srow * LDSB + sseg + 8] = bv1;
        __syncthreads();
        int k1 = k0 + 32;
        if (k1 < K) {   // issue next-chunk loads BEFORE compute (overlap)
            if (okA) {
                const uint4* gp = (const uint4*)(A + (size_t)growA * K + k1 + sseg);
                av0 = gp[0]; av1 = gp[1];
            } else { av0 = make_uint4(0, 0, 0, 0); av1 = av0; }
            const uint4* gq = (const uint4*)(B + (size_t)(n0 + srow) * K + k1 + sseg);
            bv0 = gq[0]; bv1 = gq[1];
        }
        bf16x8 af[4], bf[4];
#pragma unroll
        for (int i = 0; i < 4; ++i)
            af[i] = *(const bf16x8*)&As[(wm + i * 16 + l16) * LDSB + quad * 8];
#pragma unroll
        for (int j = 0; j < 4; ++j)
            bf[j] = *(const bf16x8*)&Bs[(wn + j * 16 + l16) * LDSB + quad * 8];
#pragma unroll
        for (int i = 0; i < 4; ++i)
#pragma unroll
            for (int j = 0; j < 4; ++j)
                acc[i][j] = __builtin_amdgcn_mfma_f32_16x16x32_bf16(
                    af[i], bf[j], acc[i][j], 0, 0, 0);
    }
    // epilogue: C/D layout col=lane&15, row=quad*4+reg
#pragma unroll
    for (int i = 0; i < 4; ++i) {
#pragma unroll
        for (int r = 0; r < 4; ++r) {
            int grow = m0 + wm + i * 16 + quad * 4 + r;
            if (grow < M) {
#pragma unroll
                for (int j = 0; j < 4; ++j) {
                    int gcol = n0 + wn + j * 16 + l16;
                    C[(size_t)grow * N + gcol] = f2bf(acc[i][j][r]);
                }
            }
        }
    }
    // fused score epilogue
    float as[4], adw[4];
#pragma unroll
    for (int j = 0; j < 4; ++j) {
        int col = n0 + wn + j * 16 + l16;   // flat index into att (H*C = N)
        as[j]  = att_s[col];
        adw[j] = att_d[col];
    }
    int head = (H == 8) ? ((n0 + wn) >> 6) : 0;
#pragma unroll
    for (int i = 0; i < 4; ++i) {
#pragma unroll
        for (int r = 0; r < 4; ++r) {
            float ps = acc[i][0][r] * as[0] + acc[i][1][r] * as[1] +
                       acc[i][2][r] * as[2] + acc[i][3][r] * as[3];
            float pd = acc[i][0][r] * adw[0] + acc[i][1][r] * adw[1] +
                       acc[i][2][r] * adw[2] + acc[i][3][r] * adw[3];
#pragma unroll
            for (int off = 1; off < 16; off <<= 1) {
                ps += __shfl_xor(ps, off);
                pd += __shfl_xor(pd, off);
            }
            int grow = m0 + wm + i * 16 + quad * 4 + r;
            if (l16 == 0 && grow < M) {
                if (H == 1) {
                    atomicAdd(&sout[grow], ps);
                    atomicAdd(&dout[grow], pd);
                } else {
                    sout[grow * 8 + head] = ps;
                    dout[grow * 8 + head] = pd;
                }
            }
        }
    }
}

// ---------------- fused gemm1 + fill_edges (independent work, block-split) ----
__global__ __launch_bounds__(256) void g1f(const ushort* __restrict__ A,
                                           const ushort* __restrict__ B,
                                           ushort* __restrict__ C,
                                           int M, int N, int K,
                                           const float* __restrict__ att_s,
                                           const float* __restrict__ att_d,
                                           float* __restrict__ sout,
                                           float* __restrict__ dout, int H,
                                           int gemmBlocks, int nby,
                                           const int* __restrict__ esrc,
                                           const int* __restrict__ edst,
                                           int* __restrict__ cursor,
                                           int* __restrict__ srcs, int E) {
    __shared__ ushort As[128 * LDSB];
    __shared__ ushort Bs[128 * LDSB];
    int blk = blockIdx.x;
    if (blk < gemmBlocks) {
        gemm_body(As, Bs, A, B, C, M, N, K, blk / nby, blk % nby,
                  att_s, att_d, sout, dout, H);
    } else {
        int e = (blk - gemmBlocks) * 256 + threadIdx.x;
        if (e < E) {
            int pos = atomicAdd(&cursor[edst[e]], 1);
            srcs[pos] = esrc[e];
        }
    }
}

// ---------------- plain GEMM kernel (layer 2) ----------------
__global__ __launch_bounds__(256) void gemm_k(const ushort* __restrict__ A,
                                              const ushort* __restrict__ B,
                                              ushort* __restrict__ C,
                                              int M, int N, int K,
                                              const float* __restrict__ att_s,
                                              const float* __restrict__ att_d,
                                              float* __restrict__ sout,
                                              float* __restrict__ dout, int H,
                                              int nby) {
    __shared__ ushort As[128 * LDSB];
    __shared__ ushort Bs[128 * LDSB];
    gemm_body(As, Bs, A, B, C, M, N, K, blockIdx.x / nby, blockIdx.x % nby,
              att_s, att_d, sout, dout, H);
}

// ---------------- CSR scan + out prefill (out = b_out per graph) ----------
__global__ __launch_bounds__(1024) void scan_offsets(const int* cnt, int* row_start,
                                                     int* cursor, int N,
                                                     const float* __restrict__ b_out,
                                                     float* __restrict__ out) {
    __shared__ int sm[1024];
    int t = threadIdx.x;
    if (t < 512) out[t] = b_out[t & 1];
    int per = (N + 1023) / 1024;
    int beg = t * per;
    int end = beg + per; if (end > N) end = N;
    int sum = 0;
    for (int i = beg; i < end; ++i) sum += cnt[i];
    sm[t] = sum;
    __syncthreads();
    for (int off = 1; off < 1024; off <<= 1) {
        int add = (t >= off) ? sm[t - off] : 0;
        __syncthreads();
        sm[t] += add;
        __syncthreads();
    }
    int run = sm[t] - sum;
    for (int i = beg; i < end; ++i) {
        int c = cnt[i];
        row_start[i] = run;
        cursor[i] = run;
        run += c;
    }
    if (t == 1023) row_start[N] = run;
}

// -------- Layer-1 softmax-aggregate (R4 structure: 4-deep unroll + tail) -----
__global__ __launch_bounds__(256) void agg1(const ushort* __restrict__ h1,
                                            const float* __restrict__ a1s,
                                            const float* __restrict__ a1d,
                                            const int* __restrict__ row_start,
                                            const int* __restrict__ srcs,
                                            const float* __restrict__ b1,
                                            ushort* __restrict__ r1, int N) {
    int node = blockIdx.x * 4 + (threadIdx.x >> 6);
    if (node >= N) return;
    int lane = threadIdx.x & 63;
    int head = lane >> 3;
    int f0 = lane * 8;
    int pbeg = row_start[node], pend = row_start[node + 1];
    float ad = a1d[node * 8 + head];
    float es = a1s[node * 8 + head] + ad;
    es = es > 0.f ? es : NEG_SLOPE * es;
    float ex_self = __expf(es);
    float den = ex_self;
    float q[8];
    unpack8(*(const uint4*)(h1 + (size_t)node * 512 + f0), q);
    float acc[8];
#pragma unroll
    for (int j = 0; j < 8; ++j) acc[j] = ex_self * q[j];
    int p = pbeg;
    for (; p + 4 <= pend; p += 4) {
        int s0 = srcs[p + 0];
        int s1 = srcs[p + 1];
        int s2 = srcs[p + 2];
        int s3 = srcs[p + 3];
        uint4 u0 = *(const uint4*)(h1 + (size_t)s0 * 512 + f0);
        uint4 u1 = *(const uint4*)(h1 + (size_t)s1 * 512 + f0);
        uint4 u2 = *(const uint4*)(h1 + (size_t)s2 * 512 + f0);
        uint4 u3 = *(const uint4*)(h1 + (size_t)s3 * 512 + f0);
        float as0 = a1s[s0 * 8 + head];
        float as1 = a1s[s1 * 8 + head];
        float as2 = a1s[s2 * 8 + head];
        float as3 = a1s[s3 * 8 + head];
        float e0 = as0 + ad; e0 = e0 > 0.f ? e0 : NEG_SLOPE * e0;
        float e1 = as1 + ad; e1 = e1 > 0.f ? e1 : NEG_SLOPE * e1;
        float e2 = as2 + ad; e2 = e2 > 0.f ? e2 : NEG_SLOPE * e2;
        float e3 = as3 + ad; e3 = e3 > 0.f ? e3 : NEG_SLOPE * e3;
        float x0 = __expf(e0), x1 = __expf(e1), x2 = __expf(e2), x3 = __expf(e3);
        den += (x0 + x1) + (x2 + x3);
        float v[8];
        unpack8(u0, v);
#pragma unroll
        for (int j = 0; j < 8; ++j) acc[j] += x0 * v[j];
        unpack8(u1, v);
#pragma unroll
        for (int j = 0; j < 8; ++j) acc[j] += x1 * v[j];
        unpack8(u2, v);
#pragma unroll
        for (int j = 0; j < 8; ++j) acc[j] += x2 * v[j];
        unpack8(u3, v);
#pragma unroll
        for (int j = 0; j < 8; ++j) acc[j] += x3 * v[j];
    }
    for (; p < pend; ++p) {
        int s = srcs[p];
        float e = a1s[s * 8 + head] + ad;
        e = e > 0.f ? e : NEG_SLOPE * e;
        float ex = __expf(e);
        den += ex;
        float v[8];
        unpack8(*(const uint4*)(h1 + (size_t)s * 512 + f0), v);
#pragma unroll
        for (int j = 0; j < 8; ++j) acc[j] += ex * v[j];
    }
    float rden = 1.0f / (den + 1e-16f);
    const float4* bp = (const float4*)(b1 + f0);
    float4 b0 = bp[0], b1v = bp[1];
    float o[8];
    o[0] = fmaxf(acc[0] * rden + b0.x, 0.f);
    o[1] = fmaxf(acc[1] * rden + b0.y, 0.f);
    o[2] = fmaxf(acc[2] * rden + b0.z, 0.f);
    o[3] = fmaxf(acc[3] * rden + b0.w, 0.f);
    o[4] = fmaxf(acc[4] * rden + b1v.x, 0.f);
    o[5] = fmaxf(acc[5] * rden + b1v.y, 0.f);
    o[6] = fmaxf(acc[6] * rden + b1v.z, 0.f);
    o[7] = fmaxf(acc[7] * rden + b1v.w, 0.f);
    uint4 ov;
    ov.x = pack2(o[0], o[1]); ov.y = pack2(o[2], o[3]);
    ov.z = pack2(o[4], o[5]); ov.w = pack2(o[6], o[7]);
    *(uint4*)(r1 + (size_t)node * 512 + f0) = ov;
}

// -------- Layer-2 aggregate + pooling + output GEMM (agg1-shaped) ------------
// 1 node / 64-lane wave, 2 bf16 feats per lane (4B loads, 256B/edge), 4-deep
// unroll with NAMED scalars (forces co-issued gathers), tail loop. Epilogue:
// w_n = attn*mask and the two W_out dots reduced across 64 lanes -> 2
// atomicAdds into out[g] (prefilled with b_out).
__global__ __launch_bounds__(256) void agg2out(const ushort* __restrict__ h2,
                                               const float* __restrict__ a2s,
                                               const float* __restrict__ a2d,
                                               const int* __restrict__ row_start,
                                               const int* __restrict__ srcs,
                                               const float* __restrict__ b2,
                                               const int* __restrict__ batch,
                                               const float* __restrict__ w_attn,
                                               const float* __restrict__ b_attn,
                                               const float* __restrict__ w_mask,
                                               const float* __restrict__ b_mask,
                                               const float* __restrict__ W_out,
                                               float* __restrict__ out, int N) {
    int node = blockIdx.x * 4 + (threadIdx.x >> 6);
    if (node >= N) return;
    int lane = threadIdx.x & 63;
    int f0 = lane * 2;                         // 2 bf16 feats per lane
    int pbeg = row_start[node], pend = row_start[node + 1];
    float ad = a2d[node];
    float es = a2s[node] + ad;
    es = es > 0.f ? es : NEG_SLOPE * es;
    float ex_self = __expf(es);
    float den = ex_self;
    unsigned uq = *(const unsigned*)(h2 + (size_t)node * 128 + f0);
    float acc0 = ex_self * bflo(uq);
    float acc1 = ex_self * bfhi(uq);
    int p = pbeg;
    for (; p + 4 <= pend; p += 4) {
        int s0 = srcs[p + 0];
        int s1 = srcs[p + 1];
        int s2 = srcs[p + 2];
        int s3 = srcs[p + 3];
        unsigned u0 = *(const unsigned*)(h2 + (size_t)s0 * 128 + f0);
        unsigned u1 = *(const unsigned*)(h2 + (size_t)s1 * 128 + f0);
        unsigned u2 = *(const unsigned*)(h2 + (size_t)s2 * 128 + f0);
        unsigned u3 = *(const unsigned*)(h2 + (size_t)s3 * 128 + f0);
        float as0 = a2s[s0];
        float as1 = a2s[s1];
        float as2 = a2s[s2];
        float as3 = a2s[s3];
        float e0 = as0 + ad; e0 = e0 > 0.f ? e0 : NEG_SLOPE * e0;
        float e1 = as1 + ad; e1 = e1 > 0.f ? e1 : NEG_SLOPE * e1;
        float e2 = as2 + ad; e2 = e2 > 0.f ? e2 : NEG_SLOPE * e2;
        float e3 = as3 + ad; e3 = e3 > 0.f ? e3 : NEG_SLOPE * e3;
        float x0 = __expf(e0), x1 = __expf(e1), x2 = __expf(e2), x3 = __expf(e3);
        den += (x0 + x1) + (x2 + x3);
        acc0 += x0 * bflo(u0); acc1 += x0 * bfhi(u0);
        acc0 += x1 * bflo(u1); acc1 += x1 * bfhi(u1);
        acc0 += x2 * bflo(u2); acc1 += x2 * bfhi(u2);
        acc0 += x3 * bflo(u3); acc1 += x3 * bfhi(u3);
    }
    for (; p < pend; ++p) {
        int s = srcs[p];
        unsigned u = *(const unsigned*)(h2 + (size_t)s * 128 + f0);
        float e = a2s[s] + ad;
        e = e > 0.f ? e : NEG_SLOPE * e;
        float ex = __expf(e);
        den += ex;
        acc0 += ex * bflo(u); acc1 += ex * bfhi(u);
    }
    float rden = 1.0f / (den + 1e-16f);
    float2 bv = *(const float2*)(b2 + f0);
    float o0 = fmaxf(acc0 * rden + bv.x, 0.f);
    float o1 = fmaxf(acc1 * rden + bv.y, 0.f);
    // ---- fused pooling + output projection ----
    float2 wa = *(const float2*)(w_attn + f0);
    float2 wm = *(const float2*)(w_mask + f0);
    float2 w0 = *(const float2*)(W_out + f0);        // W_out row 0
    float2 w1 = *(const float2*)(W_out + 128 + f0);  // W_out row 1
    float pa = o0 * wa.x + o1 * wa.y;
    float pm = o0 * wm.x + o1 * wm.y;
    float d0 = o0 * w0.x + o1 * w0.y;
    float d1 = o0 * w1.x + o1 * w1.y;
#pragma unroll
    for (int off = 1; off < 64; off <<= 1) {
        pa += __shfl_xor(pa, off);
        pm += __shfl_xor(pm, off);
        d0 += __shfl_xor(d0, off);
        d1 += __shfl_xor(d1, off);
    }
    if (lane == 0) {
        float attn = pa + b_attn[0];
        float mask = 1.0f / (1.0f + __expf(-(pm + b_mask[0])));
        float w = attn * mask;
        int g = batch[node];
        atomicAdd(&out[g * 2 + 0], w * d0);
        atomicAdd(&out[g * 2 + 1], w * d1);
    }
}

extern "C" void kernel_launch(void* const* d_in, const int* in_sizes, int n_in,
                              void* d_out, int out_size, void* d_ws, size_t ws_size,
                              hipStream_t stream) {
    const float* x        = (const float*)d_in[0];
    const int* edge_index = (const int*)d_in[1];
    const int* batch      = (const int*)d_in[2];
    const float* W1       = (const float*)d_in[3];
    const float* att_src1 = (const float*)d_in[4];
    const float* att_dst1 = (const float*)d_in[5];
    const float* b1       = (const float*)d_in[6];
    const float* W2       = (const float*)d_in[7];
    const float* att_src2 = (const float*)d_in[8];
    const float* att_dst2 = (const float*)d_in[9];
    const float* b2       = (const float*)d_in[10];
    const float* w_attn   = (const float*)d_in[11];
    const float* b_attn   = (const float*)d_in[12];
    const float* w_mask   = (const float*)d_in[13];
    const float* b_mask   = (const float*)d_in[14];
    const float* W_out    = (const float*)d_in[15];
    const float* b_out    = (const float*)d_in[16];
    float* out = (float*)d_out;

    int N = in_sizes[0] / 128;
    int E = in_sizes[1] / 2;
    const int* esrc = edge_index;
    const int* edst = edge_index + E;

    char* ws = (char*)d_ws;
    size_t off = 0;
    auto alloc = [&](size_t bytes) {
        void* p = ws + off;
        off = (off + bytes + 255) & ~(size_t)255;
        return p;
    };
    ushort* h1       = (ushort*)alloc((size_t)N * 512 * 2);   // bf16
    ushort* r1       = (ushort*)alloc((size_t)N * 512 * 2);   // bf16
    ushort* h2       = (ushort*)alloc((size_t)N * 128 * 2);   // bf16
    ushort* xb       = (ushort*)alloc((size_t)N * 128 * 2);   // bf16 x
    ushort* w1b      = (ushort*)alloc((size_t)512 * 128 * 2);
    ushort* w2b      = (ushort*)alloc((size_t)128 * 512 * 2);
    float*  a1s      = (float*)alloc((size_t)N * 8 * 4);
    float*  a1d      = (float*)alloc((size_t)N * 8 * 4);
    int*    row_start= (int*)alloc((size_t)(N + 1) * 4);
    int*    srcs     = (int*)alloc((size_t)E * 4);
    // zero-init region: cursor, a2s, a2d (contiguous, one memset)
    int*    cursor   = (int*)alloc((size_t)N * 4);
    float*  a2s      = (float*)alloc((size_t)N * 4);
    float*  a2d      = (float*)alloc((size_t)N * 4);
    size_t zspan = (size_t)((char*)(a2d + N) - (char*)cursor);
    hipMemsetAsync(cursor, 0, zspan, stream);

    dim3 b256(256);
    // prep: converts + edge count in one launch
    int nx4 = N * 128 / 4;
    int nw4 = 512 * 128 / 4;
    int cvtBlocks = (nx4 + 2 * nw4 + 255) / 256;
    int cntBlocks = (E + 255) / 256;
    prep<<<cvtBlocks + cntBlocks, b256, 0, stream>>>(x, xb, nx4, W1, w1b, nw4,
                                                     W2, w2b, nw4, cvtBlocks,
                                                     edst, cursor, E);
    scan_offsets<<<1, 1024, 0, stream>>>(cursor, row_start, cursor, N, b_out, out);
    // gemm1 (fused scores H=8) + fill_edges in one launch
    int g1Blocks = ((N + 127) / 128) * 4;
    g1f<<<g1Blocks + cntBlocks, b256, 0, stream>>>(xb, w1b, h1, N, 512, 128,
                                                   att_src1, att_dst1, a1s, a1d, 8,
                                                   g1Blocks, 4,
                                                   esrc, edst, cursor, srcs, E);
    agg1<<<(N + 3) / 4, b256, 0, stream>>>(h1, a1s, a1d, row_start, srcs, b1, r1, N);
    // layer 2 gemm (fused scores H=1, atomics into zeroed a2s/a2d)
    gemm_k<<<(N + 127) / 128, b256, 0, stream>>>(r1, w2b, h2, N, 128, 512,
                                                 att_src2, att_dst2, a2s, a2d, 1, 1);
    // layer 2 aggregate + pooling + output projection fused
    agg2out<<<(N + 3) / 4, b256, 0, stream>>>(h2, a2s, a2d, row_start, srcs, b2,
                                              batch, w_attn, b_attn, w_mask, b_mask,
                                              W_out, out, N);
}

// Round 10
// 291.664 us; speedup vs baseline: 1.0318x; 1.0318x over previous
//
#include <hip/hip_runtime.h>
#include <math.h>

// Layer-2 agg shape search: R9 (2 nodes/wave, 4-deep named uint2, pooled
// atomics)=55us; R10 (8-deep array-idx)=62; R11 (1 node/wave, 4B/lane)=78.
// Lesson: bytes-in-flight/wave is the lever (8 concurrent 256B rows wins);
// 1-node/wave halved MLP. R11's one win: out-projection epilogue (WRITE
// 40MB->1.25MB). R12 = R9 shape + that epilogue.

#define NEG_SLOPE 0.2f
#define LDSB 40

using bf16x8 = __attribute__((ext_vector_type(8))) __bf16;
using f32x4  = __attribute__((ext_vector_type(4))) float;

// ---------- bf16 helpers (storage ushort, fp32 compute) ----------
__device__ __forceinline__ ushort f2bf(float f) {
    unsigned u = __float_as_uint(f);
    unsigned r = (u + 0x7FFFu + ((u >> 16) & 1u)) >> 16;   // RNE
    return (ushort)r;
}
__device__ __forceinline__ unsigned pack2(float a, float b) {
    return (unsigned)f2bf(a) | ((unsigned)f2bf(b) << 16);
}
__device__ __forceinline__ float bflo(unsigned u) { return __uint_as_float(u << 16); }
__device__ __forceinline__ float bfhi(unsigned u) { return __uint_as_float(u & 0xFFFF0000u); }
__device__ __forceinline__ void unpack8(uint4 u, float* f) {
    f[0] = bflo(u.x); f[1] = bfhi(u.x);
    f[2] = bflo(u.y); f[3] = bfhi(u.y);
    f[4] = bflo(u.z); f[5] = bfhi(u.z);
    f[6] = bflo(u.w); f[7] = bfhi(u.w);
}
__device__ __forceinline__ void unpack4(uint2 u, float* f) {
    f[0] = bflo(u.x); f[1] = bfhi(u.x);
    f[2] = bflo(u.y); f[3] = bfhi(u.y);
}

// ---------------- prep: bf16 converts (blocks [0,cvtBlocks)) + edge count ----
__global__ __launch_bounds__(256) void prep(const float* __restrict__ x, ushort* __restrict__ xb, int nx4,
                                            const float* __restrict__ w1, ushort* __restrict__ w1b, int nw14,
                                            const float* __restrict__ w2, ushort* __restrict__ w2b, int nw24,
                                            int cvtBlocks,
                                            const int* __restrict__ edst, int* __restrict__ cnt, int E) {
    int blk = blockIdx.x;
    if (blk < cvtBlocks) {
        int j = blk * 256 + threadIdx.x;
        const float* src; ushort* dst;
        if (j < nx4) { src = x; dst = xb; }
        else {
            j -= nx4;
            if (j < nw14) { src = w1; dst = w1b; }
            else {
                j -= nw14;
                if (j >= nw24) return;
                src = w2; dst = w2b;
            }
        }
        float4 v = ((const float4*)src)[j];
        uint2 o;
        o.x = pack2(v.x, v.y);
        o.y = pack2(v.z, v.w);
        ((uint2*)dst)[j] = o;
    } else {
        int e = (blk - cvtBlocks) * 256 + threadIdx.x;
        if (e < E) atomicAdd(&cnt[edst[e]], 1);
    }
}

// ---------------- GEMM body: C[M,N]=A[M,K]*B[N,K]^T, software-pipelined ------
__device__ __forceinline__ void gemm_body(ushort* As, ushort* Bs,
                                          const ushort* __restrict__ A,
                                          const ushort* __restrict__ B,
                                          ushort* __restrict__ C,
                                          int M, int N, int K, int bx, int by,
                                          const float* __restrict__ att_s,
                                          const float* __restrict__ att_d,
                                          float* __restrict__ sout,
                                          float* __restrict__ dout, int H) {
    int t = threadIdx.x;
    int wave = t >> 6, lane = t & 63;
    int quad = lane >> 4, l16 = lane & 15;
    int m0 = bx * 128, n0 = by * 128;
    int wm = (wave & 1) * 64;
    int wn = (wave >> 1) * 64;
    int srow = t >> 1;
    int sseg = (t & 1) * 16;          // element offset (16 bf16 = 32 B)
    int growA = m0 + srow;
    bool okA = growA < M;
    f32x4 acc[4][4] = {};             // [mi][nj]
    uint4 av0, av1, bv0, bv1;
    {   // preload chunk 0
        if (okA) {
            const uint4* gp = (const uint4*)(A + (size_t)growA * K + sseg);
            av0 = gp[0]; av1 = gp[1];
        } else { av0 = make_uint4(0, 0, 0, 0); av1 = av0; }
        const uint4* gq = (const uint4*)(B + (size_t)(n0 + srow) * K + sseg);
        bv0 = gq[0]; bv1 = gq[1];
    }
    for (int k0 = 0; k0 < K; k0 += 32) {
        __syncthreads();   // previous chunk's LDS readers done
        *(uint4*)&As[srow * LDSB + sseg]     = av0;
        *(uint4*)&As[srow * LDSB + sseg + 8] = av1;
        *(uint4*)&Bs[srow * LDSB + sseg]     = bv0;
        *(uint4*)&Bs[srow * LDSB + sseg + 8] = bv1;
        __syncthreads();
        int k1 = k0 + 32;
        if (k1 < K) {   // issue next-chunk loads BEFORE compute (overlap)
            if (okA) {
                const uint4* gp = (const uint4*)(A + (size_t)growA * K + k1 + sseg);
                av0 = gp[0]; av1 = gp[1];
            } else { av0 = make_uint4(0, 0, 0, 0); av1 = av0; }
            const uint4* gq = (const uint4*)(B + (size_t)(n0 + srow) * K + k1 + sseg);
            bv0 = gq[0]; bv1 = gq[1];
        }
        bf16x8 af[4], bf[4];
#pragma unroll
        for (int i = 0; i < 4; ++i)
            af[i] = *(const bf16x8*)&As[(wm + i * 16 + l16) * LDSB + quad * 8];
#pragma unroll
        for (int j = 0; j < 4; ++j)
            bf[j] = *(const bf16x8*)&Bs[(wn + j * 16 + l16) * LDSB + quad * 8];
#pragma unroll
        for (int i = 0; i < 4; ++i)
#pragma unroll
            for (int j = 0; j < 4; ++j)
                acc[i][j] = __builtin_amdgcn_mfma_f32_16x16x32_bf16(
                    af[i], bf[j], acc[i][j], 0, 0, 0);
    }
    // epilogue: C/D layout col=lane&15, row=quad*4+reg
#pragma unroll
    for (int i = 0; i < 4; ++i) {
#pragma unroll
        for (int r = 0; r < 4; ++r) {
            int grow = m0 + wm + i * 16 + quad * 4 + r;
            if (grow < M) {
#pragma unroll
                for (int j = 0; j < 4; ++j) {
                    int gcol = n0 + wn + j * 16 + l16;
                    C[(size_t)grow * N + gcol] = f2bf(acc[i][j][r]);
                }
            }
        }
    }
    // fused score epilogue
    float as[4], adw[4];
#pragma unroll
    for (int j = 0; j < 4; ++j) {
        int col = n0 + wn + j * 16 + l16;   // flat index into att (H*C = N)
        as[j]  = att_s[col];
        adw[j] = att_d[col];
    }
    int head = (H == 8) ? ((n0 + wn) >> 6) : 0;
#pragma unroll
    for (int i = 0; i < 4; ++i) {
#pragma unroll
        for (int r = 0; r < 4; ++r) {
            float ps = acc[i][0][r] * as[0] + acc[i][1][r] * as[1] +
                       acc[i][2][r] * as[2] + acc[i][3][r] * as[3];
            float pd = acc[i][0][r] * adw[0] + acc[i][1][r] * adw[1] +
                       acc[i][2][r] * adw[2] + acc[i][3][r] * adw[3];
#pragma unroll
            for (int off = 1; off < 16; off <<= 1) {
                ps += __shfl_xor(ps, off);
                pd += __shfl_xor(pd, off);
            }
            int grow = m0 + wm + i * 16 + quad * 4 + r;
            if (l16 == 0 && grow < M) {
                if (H == 1) {
                    atomicAdd(&sout[grow], ps);
                    atomicAdd(&dout[grow], pd);
                } else {
                    sout[grow * 8 + head] = ps;
                    dout[grow * 8 + head] = pd;
                }
            }
        }
    }
}

// ---------------- fused gemm1 + fill_edges (independent work, block-split) ----
__global__ __launch_bounds__(256) void g1f(const ushort* __restrict__ A,
                                           const ushort* __restrict__ B,
                                           ushort* __restrict__ C,
                                           int M, int N, int K,
                                           const float* __restrict__ att_s,
                                           const float* __restrict__ att_d,
                                           float* __restrict__ sout,
                                           float* __restrict__ dout, int H,
                                           int gemmBlocks, int nby,
                                           const int* __restrict__ esrc,
                                           const int* __restrict__ edst,
                                           int* __restrict__ cursor,
                                           int* __restrict__ srcs, int E) {
    __shared__ ushort As[128 * LDSB];
    __shared__ ushort Bs[128 * LDSB];
    int blk = blockIdx.x;
    if (blk < gemmBlocks) {
        gemm_body(As, Bs, A, B, C, M, N, K, blk / nby, blk % nby,
                  att_s, att_d, sout, dout, H);
    } else {
        int e = (blk - gemmBlocks) * 256 + threadIdx.x;
        if (e < E) {
            int pos = atomicAdd(&cursor[edst[e]], 1);
            srcs[pos] = esrc[e];
        }
    }
}

// ---------------- plain GEMM kernel (layer 2) ----------------
__global__ __launch_bounds__(256) void gemm_k(const ushort* __restrict__ A,
                                              const ushort* __restrict__ B,
                                              ushort* __restrict__ C,
                                              int M, int N, int K,
                                              const float* __restrict__ att_s,
                                              const float* __restrict__ att_d,
                                              float* __restrict__ sout,
                                              float* __restrict__ dout, int H,
                                              int nby) {
    __shared__ ushort As[128 * LDSB];
    __shared__ ushort Bs[128 * LDSB];
    gemm_body(As, Bs, A, B, C, M, N, K, blockIdx.x / nby, blockIdx.x % nby,
              att_s, att_d, sout, dout, H);
}

// ---------------- CSR scan + out prefill (out = b_out per graph) ----------
__global__ __launch_bounds__(1024) void scan_offsets(const int* cnt, int* row_start,
                                                     int* cursor, int N,
                                                     const float* __restrict__ b_out,
                                                     float* __restrict__ out) {
    __shared__ int sm[1024];
    int t = threadIdx.x;
    if (t < 512) out[t] = b_out[t & 1];
    int per = (N + 1023) / 1024;
    int beg = t * per;
    int end = beg + per; if (end > N) end = N;
    int sum = 0;
    for (int i = beg; i < end; ++i) sum += cnt[i];
    sm[t] = sum;
    __syncthreads();
    for (int off = 1; off < 1024; off <<= 1) {
        int add = (t >= off) ? sm[t - off] : 0;
        __syncthreads();
        sm[t] += add;
        __syncthreads();
    }
    int run = sm[t] - sum;
    for (int i = beg; i < end; ++i) {
        int c = cnt[i];
        row_start[i] = run;
        cursor[i] = run;
        run += c;
    }
    if (t == 1023) row_start[N] = run;
}

// -------- Layer-1 softmax-aggregate (R4 structure: 4-deep unroll + tail) -----
__global__ __launch_bounds__(256) void agg1(const ushort* __restrict__ h1,
                                            const float* __restrict__ a1s,
                                            const float* __restrict__ a1d,
                                            const int* __restrict__ row_start,
                                            const int* __restrict__ srcs,
                                            const float* __restrict__ b1,
                                            ushort* __restrict__ r1, int N) {
    int node = blockIdx.x * 4 + (threadIdx.x >> 6);
    if (node >= N) return;
    int lane = threadIdx.x & 63;
    int head = lane >> 3;
    int f0 = lane * 8;
    int pbeg = row_start[node], pend = row_start[node + 1];
    float ad = a1d[node * 8 + head];
    float es = a1s[node * 8 + head] + ad;
    es = es > 0.f ? es : NEG_SLOPE * es;
    float ex_self = __expf(es);
    float den = ex_self;
    float q[8];
    unpack8(*(const uint4*)(h1 + (size_t)node * 512 + f0), q);
    float acc[8];
#pragma unroll
    for (int j = 0; j < 8; ++j) acc[j] = ex_self * q[j];
    int p = pbeg;
    for (; p + 4 <= pend; p += 4) {
        int s0 = srcs[p + 0];
        int s1 = srcs[p + 1];
        int s2 = srcs[p + 2];
        int s3 = srcs[p + 3];
        uint4 u0 = *(const uint4*)(h1 + (size_t)s0 * 512 + f0);
        uint4 u1 = *(const uint4*)(h1 + (size_t)s1 * 512 + f0);
        uint4 u2 = *(const uint4*)(h1 + (size_t)s2 * 512 + f0);
        uint4 u3 = *(const uint4*)(h1 + (size_t)s3 * 512 + f0);
        float as0 = a1s[s0 * 8 + head];
        float as1 = a1s[s1 * 8 + head];
        float as2 = a1s[s2 * 8 + head];
        float as3 = a1s[s3 * 8 + head];
        float e0 = as0 + ad; e0 = e0 > 0.f ? e0 : NEG_SLOPE * e0;
        float e1 = as1 + ad; e1 = e1 > 0.f ? e1 : NEG_SLOPE * e1;
        float e2 = as2 + ad; e2 = e2 > 0.f ? e2 : NEG_SLOPE * e2;
        float e3 = as3 + ad; e3 = e3 > 0.f ? e3 : NEG_SLOPE * e3;
        float x0 = __expf(e0), x1 = __expf(e1), x2 = __expf(e2), x3 = __expf(e3);
        den += (x0 + x1) + (x2 + x3);
        float v[8];
        unpack8(u0, v);
#pragma unroll
        for (int j = 0; j < 8; ++j) acc[j] += x0 * v[j];
        unpack8(u1, v);
#pragma unroll
        for (int j = 0; j < 8; ++j) acc[j] += x1 * v[j];
        unpack8(u2, v);
#pragma unroll
        for (int j = 0; j < 8; ++j) acc[j] += x2 * v[j];
        unpack8(u3, v);
#pragma unroll
        for (int j = 0; j < 8; ++j) acc[j] += x3 * v[j];
    }
    for (; p < pend; ++p) {
        int s = srcs[p];
        float e = a1s[s * 8 + head] + ad;
        e = e > 0.f ? e : NEG_SLOPE * e;
        float ex = __expf(e);
        den += ex;
        float v[8];
        unpack8(*(const uint4*)(h1 + (size_t)s * 512 + f0), v);
#pragma unroll
        for (int j = 0; j < 8; ++j) acc[j] += ex * v[j];
    }
    float rden = 1.0f / (den + 1e-16f);
    const float4* bp = (const float4*)(b1 + f0);
    float4 b0 = bp[0], b1v = bp[1];
    float o[8];
    o[0] = fmaxf(acc[0] * rden + b0.x, 0.f);
    o[1] = fmaxf(acc[1] * rden + b0.y, 0.f);
    o[2] = fmaxf(acc[2] * rden + b0.z, 0.f);
    o[3] = fmaxf(acc[3] * rden + b0.w, 0.f);
    o[4] = fmaxf(acc[4] * rden + b1v.x, 0.f);
    o[5] = fmaxf(acc[5] * rden + b1v.y, 0.f);
    o[6] = fmaxf(acc[6] * rden + b1v.z, 0.f);
    o[7] = fmaxf(acc[7] * rden + b1v.w, 0.f);
    uint4 ov;
    ov.x = pack2(o[0], o[1]); ov.y = pack2(o[2], o[3]);
    ov.z = pack2(o[4], o[5]); ov.w = pack2(o[6], o[7]);
    *(uint4*)(r1 + (size_t)node * 512 + f0) = ov;
}

// -------- Layer-2 aggregate + pooling + output GEMM (R9 shape + R11 epilogue) --
// 2 nodes / 64-lane wave (32 lanes, 4 feats = 8B per lane), 4-deep unroll with
// named scalars (8 concurrent 256B row-gathers per wave — the measured-best
// MLP config). Epilogue: w_n = attn*mask, two W_out dots, 32-lane reduce,
// 2 atomicAdds into out[g] (prefilled with b_out).
__global__ __launch_bounds__(256) void agg2out(const ushort* __restrict__ h2,
                                               const float* __restrict__ a2s,
                                               const float* __restrict__ a2d,
                                               const int* __restrict__ row_start,
                                               const int* __restrict__ srcs,
                                               const float* __restrict__ b2,
                                               const int* __restrict__ batch,
                                               const float* __restrict__ w_attn,
                                               const float* __restrict__ b_attn,
                                               const float* __restrict__ w_mask,
                                               const float* __restrict__ b_mask,
                                               const float* __restrict__ W_out,
                                               float* __restrict__ out, int N) {
    int node = blockIdx.x * 8 + (threadIdx.x >> 5);
    if (node >= N) return;
    int sub = threadIdx.x & 31;
    int f0 = sub * 4;
    int pbeg = row_start[node], pend = row_start[node + 1];
    float ad = a2d[node];
    float es = a2s[node] + ad;
    es = es > 0.f ? es : NEG_SLOPE * es;
    float ex_self = __expf(es);
    float den = ex_self;
    float q[4];
    unpack4(*(const uint2*)(h2 + (size_t)node * 128 + f0), q);
    float acc[4];
#pragma unroll
    for (int j = 0; j < 4; ++j) acc[j] = ex_self * q[j];
    int p = pbeg;
    for (; p + 4 <= pend; p += 4) {
        int s0 = srcs[p + 0];
        int s1 = srcs[p + 1];
        int s2 = srcs[p + 2];
        int s3 = srcs[p + 3];
        uint2 u0 = *(const uint2*)(h2 + (size_t)s0 * 128 + f0);
        uint2 u1 = *(const uint2*)(h2 + (size_t)s1 * 128 + f0);
        uint2 u2 = *(const uint2*)(h2 + (size_t)s2 * 128 + f0);
        uint2 u3 = *(const uint2*)(h2 + (size_t)s3 * 128 + f0);
        float as0 = a2s[s0];
        float as1 = a2s[s1];
        float as2 = a2s[s2];
        float as3 = a2s[s3];
        float e0 = as0 + ad; e0 = e0 > 0.f ? e0 : NEG_SLOPE * e0;
        float e1 = as1 + ad; e1 = e1 > 0.f ? e1 : NEG_SLOPE * e1;
        float e2 = as2 + ad; e2 = e2 > 0.f ? e2 : NEG_SLOPE * e2;
        float e3 = as3 + ad; e3 = e3 > 0.f ? e3 : NEG_SLOPE * e3;
        float x0 = __expf(e0), x1 = __expf(e1), x2 = __expf(e2), x3 = __expf(e3);
        den += (x0 + x1) + (x2 + x3);
        float v[4];
        unpack4(u0, v);
#pragma unroll
        for (int j = 0; j < 4; ++j) acc[j] += x0 * v[j];
        unpack4(u1, v);
#pragma unroll
        for (int j = 0; j < 4; ++j) acc[j] += x1 * v[j];
        unpack4(u2, v);
#pragma unroll
        for (int j = 0; j < 4; ++j) acc[j] += x2 * v[j];
        unpack4(u3, v);
#pragma unroll
        for (int j = 0; j < 4; ++j) acc[j] += x3 * v[j];
    }
    for (; p < pend; ++p) {
        int s = srcs[p];
        float e = a2s[s] + ad;
        e = e > 0.f ? e : NEG_SLOPE * e;
        float ex = __expf(e);
        den += ex;
        float v[4];
        unpack4(*(const uint2*)(h2 + (size_t)s * 128 + f0), v);
#pragma unroll
        for (int j = 0; j < 4; ++j) acc[j] += ex * v[j];
    }
    float rden = 1.0f / (den + 1e-16f);
    float4 bv = *(const float4*)(b2 + f0);
    float4 o;
    o.x = fmaxf(acc[0] * rden + bv.x, 0.f);
    o.y = fmaxf(acc[1] * rden + bv.y, 0.f);
    o.z = fmaxf(acc[2] * rden + bv.z, 0.f);
    o.w = fmaxf(acc[3] * rden + bv.w, 0.f);
    // ---- fused pooling + output projection (R11's verified WRITE fix) ----
    float4 wa = *(const float4*)(w_attn + f0);
    float4 wm = *(const float4*)(w_mask + f0);
    float4 w0 = *(const float4*)(W_out + f0);        // W_out row 0
    float4 w1 = *(const float4*)(W_out + 128 + f0);  // W_out row 1
    float pa = o.x * wa.x + o.y * wa.y + o.z * wa.z + o.w * wa.w;
    float pm = o.x * wm.x + o.y * wm.y + o.z * wm.z + o.w * wm.w;
    float d0 = o.x * w0.x + o.y * w0.y + o.z * w0.z + o.w * w0.w;
    float d1 = o.x * w1.x + o.y * w1.y + o.z * w1.z + o.w * w1.w;
#pragma unroll
    for (int off = 1; off < 32; off <<= 1) {
        pa += __shfl_xor(pa, off);
        pm += __shfl_xor(pm, off);
        d0 += __shfl_xor(d0, off);
        d1 += __shfl_xor(d1, off);
    }
    if (sub == 0) {
        float attn = pa + b_attn[0];
        float mask = 1.0f / (1.0f + __expf(-(pm + b_mask[0])));
        float w = attn * mask;
        int g = batch[node];
        atomicAdd(&out[g * 2 + 0], w * d0);
        atomicAdd(&out[g * 2 + 1], w * d1);
    }
}

extern "C" void kernel_launch(void* const* d_in, const int* in_sizes, int n_in,
                              void* d_out, int out_size, void* d_ws, size_t ws_size,
                              hipStream_t stream) {
    const float* x        = (const float*)d_in[0];
    const int* edge_index = (const int*)d_in[1];
    const int* batch      = (const int*)d_in[2];
    const float* W1       = (const float*)d_in[3];
    const float* att_src1 = (const float*)d_in[4];
    const float* att_dst1 = (const float*)d_in[5];
    const float* b1       = (const float*)d_in[6];
    const float* W2       = (const float*)d_in[7];
    const float* att_src2 = (const float*)d_in[8];
    const float* att_dst2 = (const float*)d_in[9];
    const float* b2       = (const float*)d_in[10];
    const float* w_attn   = (const float*)d_in[11];
    const float* b_attn   = (const float*)d_in[12];
    const float* w_mask   = (const float*)d_in[13];
    const float* b_mask   = (const float*)d_in[14];
    const float* W_out    = (const float*)d_in[15];
    const float* b_out    = (const float*)d_in[16];
    float* out = (float*)d_out;

    int N = in_sizes[0] / 128;
    int E = in_sizes[1] / 2;
    const int* esrc = edge_index;
    const int* edst = edge_index + E;

    char* ws = (char*)d_ws;
    size_t off = 0;
    auto alloc = [&](size_t bytes) {
        void* p = ws + off;
        off = (off + bytes + 255) & ~(size_t)255;
        return p;
    };
    ushort* h1       = (ushort*)alloc((size_t)N * 512 * 2);   // bf16
    ushort* r1       = (ushort*)alloc((size_t)N * 512 * 2);   // bf16
    ushort* h2       = (ushort*)alloc((size_t)N * 128 * 2);   // bf16
    ushort* xb       = (ushort*)alloc((size_t)N * 128 * 2);   // bf16 x
    ushort* w1b      = (ushort*)alloc((size_t)512 * 128 * 2);
    ushort* w2b      = (ushort*)alloc((size_t)128 * 512 * 2);
    float*  a1s      = (float*)alloc((size_t)N * 8 * 4);
    float*  a1d      = (float*)alloc((size_t)N * 8 * 4);
    int*    row_start= (int*)alloc((size_t)(N + 1) * 4);
    int*    srcs     = (int*)alloc((size_t)E * 4);
    // zero-init region: cursor, a2s, a2d (contiguous, one memset)
    int*    cursor   = (int*)alloc((size_t)N * 4);
    float*  a2s      = (float*)alloc((size_t)N * 4);
    float*  a2d      = (float*)alloc((size_t)N * 4);
    size_t zspan = (size_t)((char*)(a2d + N) - (char*)cursor);
    hipMemsetAsync(cursor, 0, zspan, stream);

    dim3 b256(256);
    // prep: converts + edge count in one launch
    int nx4 = N * 128 / 4;
    int nw4 = 512 * 128 / 4;
    int cvtBlocks = (nx4 + 2 * nw4 + 255) / 256;
    int cntBlocks = (E + 255) / 256;
    prep<<<cvtBlocks + cntBlocks, b256, 0, stream>>>(x, xb, nx4, W1, w1b, nw4,
                                                     W2, w2b, nw4, cvtBlocks,
                                                     edst, cursor, E);
    scan_offsets<<<1, 1024, 0, stream>>>(cursor, row_start, cursor, N, b_out, out);
    // gemm1 (fused scores H=8) + fill_edges in one launch
    int g1Blocks = ((N + 127) / 128) * 4;
    g1f<<<g1Blocks + cntBlocks, b256, 0, stream>>>(xb, w1b, h1, N, 512, 128,
                                                   att_src1, att_dst1, a1s, a1d, 8,
                                                   g1Blocks, 4,
                                                   esrc, edst, cursor, srcs, E);
    agg1<<<(N + 3) / 4, b256, 0, stream>>>(h1, a1s, a1d, row_start, srcs, b1, r1, N);
    // layer 2 gemm (fused scores H=1, atomics into zeroed a2s/a2d)
    gemm_k<<<(N + 127) / 128, b256, 0, stream>>>(r1, w2b, h2, N, 128, 512,
                                                 att_src2, att_dst2, a2s, a2d, 1, 1);
    // layer 2 aggregate + pooling + output projection fused
    agg2out<<<(N + 7) / 8, b256, 0, stream>>>(h2, a2s, a2d, row_start, srcs, b2,
                                              batch, w_attn, b_attn, w_mask, b_mask,
                                              W_out, out, N);
}

// Round 11
// 284.253 us; speedup vs baseline: 1.0587x; 1.0261x over previous
//
#include <hip/hip_runtime.h>
#include <math.h>

// Layer-2 agg history: R9 (2n/wave,4-deep,8B/lane)=55; R10 (8-deep array)=62.7;
// R11 (1n/wave,4B)=78; R12 (R9+out-epilogue)=66. Cross-kernel insight: agg1
// (1KB rows) and agg2 (256B rows) cost the SAME ~160ns/edge => transaction-
// bound, not byte-bound. agg1's geometry (16B/lane loads, 4-deep named) keeps
// 32 lines in flight and is codegen-proven.
// R13: agg2out = 4 nodes/wave (16-lane groups), 16B uint4 per lane (full 256B
// row per group), 4-deep named unroll => 16 row-gathers in flight/wave (2x R9).
// Epilogue: 4 dots over 8 feats, 4-step 16-lane reduce, 2 atomics/node.

#define NEG_SLOPE 0.2f
#define LDSB 40

using bf16x8 = __attribute__((ext_vector_type(8))) __bf16;
using f32x4  = __attribute__((ext_vector_type(4))) float;

// ---------- bf16 helpers (storage ushort, fp32 compute) ----------
__device__ __forceinline__ ushort f2bf(float f) {
    unsigned u = __float_as_uint(f);
    unsigned r = (u + 0x7FFFu + ((u >> 16) & 1u)) >> 16;   // RNE
    return (ushort)r;
}
__device__ __forceinline__ unsigned pack2(float a, float b) {
    return (unsigned)f2bf(a) | ((unsigned)f2bf(b) << 16);
}
__device__ __forceinline__ float bflo(unsigned u) { return __uint_as_float(u << 16); }
__device__ __forceinline__ float bfhi(unsigned u) { return __uint_as_float(u & 0xFFFF0000u); }
__device__ __forceinline__ void unpack8(uint4 u, float* f) {
    f[0] = bflo(u.x); f[1] = bfhi(u.x);
    f[2] = bflo(u.y); f[3] = bfhi(u.y);
    f[4] = bflo(u.z); f[5] = bfhi(u.z);
    f[6] = bflo(u.w); f[7] = bfhi(u.w);
}

// ---------------- prep: bf16 converts (blocks [0,cvtBlocks)) + edge count ----
__global__ __launch_bounds__(256) void prep(const float* __restrict__ x, ushort* __restrict__ xb, int nx4,
                                            const float* __restrict__ w1, ushort* __restrict__ w1b, int nw14,
                                            const float* __restrict__ w2, ushort* __restrict__ w2b, int nw24,
                                            int cvtBlocks,
                                            const int* __restrict__ edst, int* __restrict__ cnt, int E) {
    int blk = blockIdx.x;
    if (blk < cvtBlocks) {
        int j = blk * 256 + threadIdx.x;
        const float* src; ushort* dst;
        if (j < nx4) { src = x; dst = xb; }
        else {
            j -= nx4;
            if (j < nw14) { src = w1; dst = w1b; }
            else {
                j -= nw14;
                if (j >= nw24) return;
                src = w2; dst = w2b;
            }
        }
        float4 v = ((const float4*)src)[j];
        uint2 o;
        o.x = pack2(v.x, v.y);
        o.y = pack2(v.z, v.w);
        ((uint2*)dst)[j] = o;
    } else {
        int e = (blk - cvtBlocks) * 256 + threadIdx.x;
        if (e < E) atomicAdd(&cnt[edst[e]], 1);
    }
}

// ---------------- GEMM body: C[M,N]=A[M,K]*B[N,K]^T, software-pipelined ------
__device__ __forceinline__ void gemm_body(ushort* As, ushort* Bs,
                                          const ushort* __restrict__ A,
                                          const ushort* __restrict__ B,
                                          ushort* __restrict__ C,
                                          int M, int N, int K, int bx, int by,
                                          const float* __restrict__ att_s,
                                          const float* __restrict__ att_d,
                                          float* __restrict__ sout,
                                          float* __restrict__ dout, int H) {
    int t = threadIdx.x;
    int wave = t >> 6, lane = t & 63;
    int quad = lane >> 4, l16 = lane & 15;
    int m0 = bx * 128, n0 = by * 128;
    int wm = (wave & 1) * 64;
    int wn = (wave >> 1) * 64;
    int srow = t >> 1;
    int sseg = (t & 1) * 16;          // element offset (16 bf16 = 32 B)
    int growA = m0 + srow;
    bool okA = growA < M;
    f32x4 acc[4][4] = {};             // [mi][nj]
    uint4 av0, av1, bv0, bv1;
    {   // preload chunk 0
        if (okA) {
            const uint4* gp = (const uint4*)(A + (size_t)growA * K + sseg);
            av0 = gp[0]; av1 = gp[1];
        } else { av0 = make_uint4(0, 0, 0, 0); av1 = av0; }
        const uint4* gq = (const uint4*)(B + (size_t)(n0 + srow) * K + sseg);
        bv0 = gq[0]; bv1 = gq[1];
    }
    for (int k0 = 0; k0 < K; k0 += 32) {
        __syncthreads();   // previous chunk's LDS readers done
        *(uint4*)&As[srow * LDSB + sseg]     = av0;
        *(uint4*)&As[srow * LDSB + sseg + 8] = av1;
        *(uint4*)&Bs[srow * LDSB + sseg]     = bv0;
        *(uint4*)&Bs[srow * LDSB + sseg + 8] = bv1;
        __syncthreads();
        int k1 = k0 + 32;
        if (k1 < K) {   // issue next-chunk loads BEFORE compute (overlap)
            if (okA) {
                const uint4* gp = (const uint4*)(A + (size_t)growA * K + k1 + sseg);
                av0 = gp[0]; av1 = gp[1];
            } else { av0 = make_uint4(0, 0, 0, 0); av1 = av0; }
            const uint4* gq = (const uint4*)(B + (size_t)(n0 + srow) * K + k1 + sseg);
            bv0 = gq[0]; bv1 = gq[1];
        }
        bf16x8 af[4], bf[4];
#pragma unroll
        for (int i = 0; i < 4; ++i)
            af[i] = *(const bf16x8*)&As[(wm + i * 16 + l16) * LDSB + quad * 8];
#pragma unroll
        for (int j = 0; j < 4; ++j)
            bf[j] = *(const bf16x8*)&Bs[(wn + j * 16 + l16) * LDSB + quad * 8];
#pragma unroll
        for (int i = 0; i < 4; ++i)
#pragma unroll
            for (int j = 0; j < 4; ++j)
                acc[i][j] = __builtin_amdgcn_mfma_f32_16x16x32_bf16(
                    af[i], bf[j], acc[i][j], 0, 0, 0);
    }
    // epilogue: C/D layout col=lane&15, row=quad*4+reg
#pragma unroll
    for (int i = 0; i < 4; ++i) {
#pragma unroll
        for (int r = 0; r < 4; ++r) {
            int grow = m0 + wm + i * 16 + quad * 4 + r;
            if (grow < M) {
#pragma unroll
                for (int j = 0; j < 4; ++j) {
                    int gcol = n0 + wn + j * 16 + l16;
                    C[(size_t)grow * N + gcol] = f2bf(acc[i][j][r]);
                }
            }
        }
    }
    // fused score epilogue
    float as[4], adw[4];
#pragma unroll
    for (int j = 0; j < 4; ++j) {
        int col = n0 + wn + j * 16 + l16;   // flat index into att (H*C = N)
        as[j]  = att_s[col];
        adw[j] = att_d[col];
    }
    int head = (H == 8) ? ((n0 + wn) >> 6) : 0;
#pragma unroll
    for (int i = 0; i < 4; ++i) {
#pragma unroll
        for (int r = 0; r < 4; ++r) {
            float ps = acc[i][0][r] * as[0] + acc[i][1][r] * as[1] +
                       acc[i][2][r] * as[2] + acc[i][3][r] * as[3];
            float pd = acc[i][0][r] * adw[0] + acc[i][1][r] * adw[1] +
                       acc[i][2][r] * adw[2] + acc[i][3][r] * adw[3];
#pragma unroll
            for (int off = 1; off < 16; off <<= 1) {
                ps += __shfl_xor(ps, off);
                pd += __shfl_xor(pd, off);
            }
            int grow = m0 + wm + i * 16 + quad * 4 + r;
            if (l16 == 0 && grow < M) {
                if (H == 1) {
                    atomicAdd(&sout[grow], ps);
                    atomicAdd(&dout[grow], pd);
                } else {
                    sout[grow * 8 + head] = ps;
                    dout[grow * 8 + head] = pd;
                }
            }
        }
    }
}

// ---------------- fused gemm1 + fill_edges (independent work, block-split) ----
__global__ __launch_bounds__(256) void g1f(const ushort* __restrict__ A,
                                           const ushort* __restrict__ B,
                                           ushort* __restrict__ C,
                                           int M, int N, int K,
                                           const float* __restrict__ att_s,
                                           const float* __restrict__ att_d,
                                           float* __restrict__ sout,
                                           float* __restrict__ dout, int H,
                                           int gemmBlocks, int nby,
                                           const int* __restrict__ esrc,
                                           const int* __restrict__ edst,
                                           int* __restrict__ cursor,
                                           int* __restrict__ srcs, int E) {
    __shared__ ushort As[128 * LDSB];
    __shared__ ushort Bs[128 * LDSB];
    int blk = blockIdx.x;
    if (blk < gemmBlocks) {
        gemm_body(As, Bs, A, B, C, M, N, K, blk / nby, blk % nby,
                  att_s, att_d, sout, dout, H);
    } else {
        int e = (blk - gemmBlocks) * 256 + threadIdx.x;
        if (e < E) {
            int pos = atomicAdd(&cursor[edst[e]], 1);
            srcs[pos] = esrc[e];
        }
    }
}

// ---------------- plain GEMM kernel (layer 2) ----------------
__global__ __launch_bounds__(256) void gemm_k(const ushort* __restrict__ A,
                                              const ushort* __restrict__ B,
                                              ushort* __restrict__ C,
                                              int M, int N, int K,
                                              const float* __restrict__ att_s,
                                              const float* __restrict__ att_d,
                                              float* __restrict__ sout,
                                              float* __restrict__ dout, int H,
                                              int nby) {
    __shared__ ushort As[128 * LDSB];
    __shared__ ushort Bs[128 * LDSB];
    gemm_body(As, Bs, A, B, C, M, N, K, blockIdx.x / nby, blockIdx.x % nby,
              att_s, att_d, sout, dout, H);
}

// ---------------- CSR scan + out prefill (out = b_out per graph) ----------
__global__ __launch_bounds__(1024) void scan_offsets(const int* cnt, int* row_start,
                                                     int* cursor, int N,
                                                     const float* __restrict__ b_out,
                                                     float* __restrict__ out) {
    __shared__ int sm[1024];
    int t = threadIdx.x;
    if (t < 512) out[t] = b_out[t & 1];
    int per = (N + 1023) / 1024;
    int beg = t * per;
    int end = beg + per; if (end > N) end = N;
    int sum = 0;
    for (int i = beg; i < end; ++i) sum += cnt[i];
    sm[t] = sum;
    __syncthreads();
    for (int off = 1; off < 1024; off <<= 1) {
        int add = (t >= off) ? sm[t - off] : 0;
        __syncthreads();
        sm[t] += add;
        __syncthreads();
    }
    int run = sm[t] - sum;
    for (int i = beg; i < end; ++i) {
        int c = cnt[i];
        row_start[i] = run;
        cursor[i] = run;
        run += c;
    }
    if (t == 1023) row_start[N] = run;
}

// -------- Layer-1 softmax-aggregate (R4 structure: 4-deep unroll + tail) -----
__global__ __launch_bounds__(256) void agg1(const ushort* __restrict__ h1,
                                            const float* __restrict__ a1s,
                                            const float* __restrict__ a1d,
                                            const int* __restrict__ row_start,
                                            const int* __restrict__ srcs,
                                            const float* __restrict__ b1,
                                            ushort* __restrict__ r1, int N) {
    int node = blockIdx.x * 4 + (threadIdx.x >> 6);
    if (node >= N) return;
    int lane = threadIdx.x & 63;
    int head = lane >> 3;
    int f0 = lane * 8;
    int pbeg = row_start[node], pend = row_start[node + 1];
    float ad = a1d[node * 8 + head];
    float es = a1s[node * 8 + head] + ad;
    es = es > 0.f ? es : NEG_SLOPE * es;
    float ex_self = __expf(es);
    float den = ex_self;
    float q[8];
    unpack8(*(const uint4*)(h1 + (size_t)node * 512 + f0), q);
    float acc[8];
#pragma unroll
    for (int j = 0; j < 8; ++j) acc[j] = ex_self * q[j];
    int p = pbeg;
    for (; p + 4 <= pend; p += 4) {
        int s0 = srcs[p + 0];
        int s1 = srcs[p + 1];
        int s2 = srcs[p + 2];
        int s3 = srcs[p + 3];
        uint4 u0 = *(const uint4*)(h1 + (size_t)s0 * 512 + f0);
        uint4 u1 = *(const uint4*)(h1 + (size_t)s1 * 512 + f0);
        uint4 u2 = *(const uint4*)(h1 + (size_t)s2 * 512 + f0);
        uint4 u3 = *(const uint4*)(h1 + (size_t)s3 * 512 + f0);
        float as0 = a1s[s0 * 8 + head];
        float as1 = a1s[s1 * 8 + head];
        float as2 = a1s[s2 * 8 + head];
        float as3 = a1s[s3 * 8 + head];
        float e0 = as0 + ad; e0 = e0 > 0.f ? e0 : NEG_SLOPE * e0;
        float e1 = as1 + ad; e1 = e1 > 0.f ? e1 : NEG_SLOPE * e1;
        float e2 = as2 + ad; e2 = e2 > 0.f ? e2 : NEG_SLOPE * e2;
        float e3 = as3 + ad; e3 = e3 > 0.f ? e3 : NEG_SLOPE * e3;
        float x0 = __expf(e0), x1 = __expf(e1), x2 = __expf(e2), x3 = __expf(e3);
        den += (x0 + x1) + (x2 + x3);
        float v[8];
        unpack8(u0, v);
#pragma unroll
        for (int j = 0; j < 8; ++j) acc[j] += x0 * v[j];
        unpack8(u1, v);
#pragma unroll
        for (int j = 0; j < 8; ++j) acc[j] += x1 * v[j];
        unpack8(u2, v);
#pragma unroll
        for (int j = 0; j < 8; ++j) acc[j] += x2 * v[j];
        unpack8(u3, v);
#pragma unroll
        for (int j = 0; j < 8; ++j) acc[j] += x3 * v[j];
    }
    for (; p < pend; ++p) {
        int s = srcs[p];
        float e = a1s[s * 8 + head] + ad;
        e = e > 0.f ? e : NEG_SLOPE * e;
        float ex = __expf(e);
        den += ex;
        float v[8];
        unpack8(*(const uint4*)(h1 + (size_t)s * 512 + f0), v);
#pragma unroll
        for (int j = 0; j < 8; ++j) acc[j] += ex * v[j];
    }
    float rden = 1.0f / (den + 1e-16f);
    const float4* bp = (const float4*)(b1 + f0);
    float4 b0 = bp[0], b1v = bp[1];
    float o[8];
    o[0] = fmaxf(acc[0] * rden + b0.x, 0.f);
    o[1] = fmaxf(acc[1] * rden + b0.y, 0.f);
    o[2] = fmaxf(acc[2] * rden + b0.z, 0.f);
    o[3] = fmaxf(acc[3] * rden + b0.w, 0.f);
    o[4] = fmaxf(acc[4] * rden + b1v.x, 0.f);
    o[5] = fmaxf(acc[5] * rden + b1v.y, 0.f);
    o[6] = fmaxf(acc[6] * rden + b1v.z, 0.f);
    o[7] = fmaxf(acc[7] * rden + b1v.w, 0.f);
    uint4 ov;
    ov.x = pack2(o[0], o[1]); ov.y = pack2(o[2], o[3]);
    ov.z = pack2(o[4], o[5]); ov.w = pack2(o[6], o[7]);
    *(uint4*)(r1 + (size_t)node * 512 + f0) = ov;
}

// -------- Layer-2 aggregate + pooling + output GEMM (agg1 geometry) ----------
// 4 nodes / 64-lane wave (16-lane groups), each lane loads uint4 = 16B =
// 8 feats of the 256B row (exact agg1 per-lane load width), 4-deep NAMED
// unroll => 16 row-gathers (32 lines) in flight per wave, 2x R9's best.
// Epilogue: 4 dots over 8 feats, 4-step 16-lane reduce, 2 atomics/node into
// out (prefilled with b_out).
__global__ __launch_bounds__(256) void agg2out(const ushort* __restrict__ h2,
                                               const float* __restrict__ a2s,
                                               const float* __restrict__ a2d,
                                               const int* __restrict__ row_start,
                                               const int* __restrict__ srcs,
                                               const float* __restrict__ b2,
                                               const int* __restrict__ batch,
                                               const float* __restrict__ w_attn,
                                               const float* __restrict__ b_attn,
                                               const float* __restrict__ w_mask,
                                               const float* __restrict__ b_mask,
                                               const float* __restrict__ W_out,
                                               float* __restrict__ out, int N) {
    int node = blockIdx.x * 16 + (threadIdx.x >> 4);
    if (node >= N) return;
    int sub = threadIdx.x & 15;
    int f0 = sub * 8;                          // 8 feats (16B) per lane
    int pbeg = row_start[node], pend = row_start[node + 1];
    float ad = a2d[node];
    float es = a2s[node] + ad;
    es = es > 0.f ? es : NEG_SLOPE * es;
    float ex_self = __expf(es);
    float den = ex_self;
    float q[8];
    unpack8(*(const uint4*)(h2 + (size_t)node * 128 + f0), q);
    float acc[8];
#pragma unroll
    for (int j = 0; j < 8; ++j) acc[j] = ex_self * q[j];
    int p = pbeg;
    for (; p + 4 <= pend; p += 4) {
        int s0 = srcs[p + 0];
        int s1 = srcs[p + 1];
        int s2 = srcs[p + 2];
        int s3 = srcs[p + 3];
        uint4 u0 = *(const uint4*)(h2 + (size_t)s0 * 128 + f0);
        uint4 u1 = *(const uint4*)(h2 + (size_t)s1 * 128 + f0);
        uint4 u2 = *(const uint4*)(h2 + (size_t)s2 * 128 + f0);
        uint4 u3 = *(const uint4*)(h2 + (size_t)s3 * 128 + f0);
        float as0 = a2s[s0];
        float as1 = a2s[s1];
        float as2 = a2s[s2];
        float as3 = a2s[s3];
        float e0 = as0 + ad; e0 = e0 > 0.f ? e0 : NEG_SLOPE * e0;
        float e1 = as1 + ad; e1 = e1 > 0.f ? e1 : NEG_SLOPE * e1;
        float e2 = as2 + ad; e2 = e2 > 0.f ? e2 : NEG_SLOPE * e2;
        float e3 = as3 + ad; e3 = e3 > 0.f ? e3 : NEG_SLOPE * e3;
        float x0 = __expf(e0), x1 = __expf(e1), x2 = __expf(e2), x3 = __expf(e3);
        den += (x0 + x1) + (x2 + x3);
        float v[8];
        unpack8(u0, v);
#pragma unroll
        for (int j = 0; j < 8; ++j) acc[j] += x0 * v[j];
        unpack8(u1, v);
#pragma unroll
        for (int j = 0; j < 8; ++j) acc[j] += x1 * v[j];
        unpack8(u2, v);
#pragma unroll
        for (int j = 0; j < 8; ++j) acc[j] += x2 * v[j];
        unpack8(u3, v);
#pragma unroll
        for (int j = 0; j < 8; ++j) acc[j] += x3 * v[j];
    }
    for (; p < pend; ++p) {
        int s = srcs[p];
        float e = a2s[s] + ad;
        e = e > 0.f ? e : NEG_SLOPE * e;
        float ex = __expf(e);
        den += ex;
        float v[8];
        unpack8(*(const uint4*)(h2 + (size_t)s * 128 + f0), v);
#pragma unroll
        for (int j = 0; j < 8; ++j) acc[j] += ex * v[j];
    }
    float rden = 1.0f / (den + 1e-16f);
    const float4* bp = (const float4*)(b2 + f0);
    float4 b0 = bp[0], b1v = bp[1];
    float o[8];
    o[0] = fmaxf(acc[0] * rden + b0.x, 0.f);
    o[1] = fmaxf(acc[1] * rden + b0.y, 0.f);
    o[2] = fmaxf(acc[2] * rden + b0.z, 0.f);
    o[3] = fmaxf(acc[3] * rden + b0.w, 0.f);
    o[4] = fmaxf(acc[4] * rden + b1v.x, 0.f);
    o[5] = fmaxf(acc[5] * rden + b1v.y, 0.f);
    o[6] = fmaxf(acc[6] * rden + b1v.z, 0.f);
    o[7] = fmaxf(acc[7] * rden + b1v.w, 0.f);
    // ---- fused pooling + output projection ----
    const float4* wap = (const float4*)(w_attn + f0);
    const float4* wmp = (const float4*)(w_mask + f0);
    const float4* w0p = (const float4*)(W_out + f0);
    const float4* w1p = (const float4*)(W_out + 128 + f0);
    float4 wa0 = wap[0], wa1 = wap[1];
    float4 wm0 = wmp[0], wm1 = wmp[1];
    float4 wo0 = w0p[0], wo1 = w0p[1];
    float4 wp0 = w1p[0], wp1 = w1p[1];
    float pa = o[0] * wa0.x + o[1] * wa0.y + o[2] * wa0.z + o[3] * wa0.w +
               o[4] * wa1.x + o[5] * wa1.y + o[6] * wa1.z + o[7] * wa1.w;
    float pm = o[0] * wm0.x + o[1] * wm0.y + o[2] * wm0.z + o[3] * wm0.w +
               o[4] * wm1.x + o[5] * wm1.y + o[6] * wm1.z + o[7] * wm1.w;
    float d0 = o[0] * wo0.x + o[1] * wo0.y + o[2] * wo0.z + o[3] * wo0.w +
               o[4] * wo1.x + o[5] * wo1.y + o[6] * wo1.z + o[7] * wo1.w;
    float d1 = o[0] * wp0.x + o[1] * wp0.y + o[2] * wp0.z + o[3] * wp0.w +
               o[4] * wp1.x + o[5] * wp1.y + o[6] * wp1.z + o[7] * wp1.w;
#pragma unroll
    for (int off = 1; off < 16; off <<= 1) {
        pa += __shfl_xor(pa, off);
        pm += __shfl_xor(pm, off);
        d0 += __shfl_xor(d0, off);
        d1 += __shfl_xor(d1, off);
    }
    if (sub == 0) {
        float attn = pa + b_attn[0];
        float mask = 1.0f / (1.0f + __expf(-(pm + b_mask[0])));
        float w = attn * mask;
        int g = batch[node];
        atomicAdd(&out[g * 2 + 0], w * d0);
        atomicAdd(&out[g * 2 + 1], w * d1);
    }
}

extern "C" void kernel_launch(void* const* d_in, const int* in_sizes, int n_in,
                              void* d_out, int out_size, void* d_ws, size_t ws_size,
                              hipStream_t stream) {
    const float* x        = (const float*)d_in[0];
    const int* edge_index = (const int*)d_in[1];
    const int* batch      = (const int*)d_in[2];
    const float* W1       = (const float*)d_in[3];
    const float* att_src1 = (const float*)d_in[4];
    const float* att_dst1 = (const float*)d_in[5];
    const float* b1       = (const float*)d_in[6];
    const float* W2       = (const float*)d_in[7];
    const float* att_src2 = (const float*)d_in[8];
    const float* att_dst2 = (const float*)d_in[9];
    const float* b2       = (const float*)d_in[10];
    const float* w_attn   = (const float*)d_in[11];
    const float* b_attn   = (const float*)d_in[12];
    const float* w_mask   = (const float*)d_in[13];
    const float* b_mask   = (const float*)d_in[14];
    const float* W_out    = (const float*)d_in[15];
    const float* b_out    = (const float*)d_in[16];
    float* out = (float*)d_out;

    int N = in_sizes[0] / 128;
    int E = in_sizes[1] / 2;
    const int* esrc = edge_index;
    const int* edst = edge_index + E;

    char* ws = (char*)d_ws;
    size_t off = 0;
    auto alloc = [&](size_t bytes) {
        void* p = ws + off;
        off = (off + bytes + 255) & ~(size_t)255;
        return p;
    };
    ushort* h1       = (ushort*)alloc((size_t)N * 512 * 2);   // bf16
    ushort* r1       = (ushort*)alloc((size_t)N * 512 * 2);   // bf16
    ushort* h2       = (ushort*)alloc((size_t)N * 128 * 2);   // bf16
    ushort* xb       = (ushort*)alloc((size_t)N * 128 * 2);   // bf16 x
    ushort* w1b      = (ushort*)alloc((size_t)512 * 128 * 2);
    ushort* w2b      = (ushort*)alloc((size_t)128 * 512 * 2);
    float*  a1s      = (float*)alloc((size_t)N * 8 * 4);
    float*  a1d      = (float*)alloc((size_t)N * 8 * 4);
    int*    row_start= (int*)alloc((size_t)(N + 1) * 4);
    int*    srcs     = (int*)alloc((size_t)E * 4);
    // zero-init region: cursor, a2s, a2d (contiguous, one memset)
    int*    cursor   = (int*)alloc((size_t)N * 4);
    float*  a2s      = (float*)alloc((size_t)N * 4);
    float*  a2d      = (float*)alloc((size_t)N * 4);
    size_t zspan = (size_t)((char*)(a2d + N) - (char*)cursor);
    hipMemsetAsync(cursor, 0, zspan, stream);

    dim3 b256(256);
    // prep: converts + edge count in one launch
    int nx4 = N * 128 / 4;
    int nw4 = 512 * 128 / 4;
    int cvtBlocks = (nx4 + 2 * nw4 + 255) / 256;
    int cntBlocks = (E + 255) / 256;
    prep<<<cvtBlocks + cntBlocks, b256, 0, stream>>>(x, xb, nx4, W1, w1b, nw4,
                                                     W2, w2b, nw4, cvtBlocks,
                                                     edst, cursor, E);
    scan_offsets<<<1, 1024, 0, stream>>>(cursor, row_start, cursor, N, b_out, out);
    // gemm1 (fused scores H=8) + fill_edges in one launch
    int g1Blocks = ((N + 127) / 128) * 4;
    g1f<<<g1Blocks + cntBlocks, b256, 0, stream>>>(xb, w1b, h1, N, 512, 128,
                                                   att_src1, att_dst1, a1s, a1d, 8,
                                                   g1Blocks, 4,
                                                   esrc, edst, cursor, srcs, E);
    agg1<<<(N + 3) / 4, b256, 0, stream>>>(h1, a1s, a1d, row_start, srcs, b1, r1, N);
    // layer 2 gemm (fused scores H=1, atomics into zeroed a2s/a2d)
    gemm_k<<<(N + 127) / 128, b256, 0, stream>>>(r1, w2b, h2, N, 128, 512,
                                                 att_src2, att_dst2, a2s, a2d, 1, 1);
    // layer 2 aggregate + pooling + output projection fused
    agg2out<<<(N + 15) / 16, b256, 0, stream>>>(h2, a2s, a2d, row_start, srcs, b2,
                                                batch, w_attn, b_attn, w_mask, b_mask,
                                                W_out, out, N);
}

// Round 12
// 280.604 us; speedup vs baseline: 1.0725x; 1.0130x over previous
//
#include <hip/hip_runtime.h>
#include <math.h>

// Layer-2 agg history: R9=55, R10=62.7, R11=78, R12=66, R13 (4 nodes/wave,
// 16-lane groups, uint4/lane, 4-deep named)=51.1 — best. Counters at R13:
// occ 28% (not VGPR-bound), BW 0.43 TB/s, VALU 11% => loop-carried latency:
// batch i+1's srcs->gather chain waits for batch i's consume.
// R14: explicit 2-stage software pipeline in agg2out (named double-buffer:
// issue batch i+1 loads before consuming batch i). Single-variable change.

#define NEG_SLOPE 0.2f
#define LDSB 40

using bf16x8 = __attribute__((ext_vector_type(8))) __bf16;
using f32x4  = __attribute__((ext_vector_type(4))) float;

// ---------- bf16 helpers (storage ushort, fp32 compute) ----------
__device__ __forceinline__ ushort f2bf(float f) {
    unsigned u = __float_as_uint(f);
    unsigned r = (u + 0x7FFFu + ((u >> 16) & 1u)) >> 16;   // RNE
    return (ushort)r;
}
__device__ __forceinline__ unsigned pack2(float a, float b) {
    return (unsigned)f2bf(a) | ((unsigned)f2bf(b) << 16);
}
__device__ __forceinline__ float bflo(unsigned u) { return __uint_as_float(u << 16); }
__device__ __forceinline__ float bfhi(unsigned u) { return __uint_as_float(u & 0xFFFF0000u); }
__device__ __forceinline__ void unpack8(uint4 u, float* f) {
    f[0] = bflo(u.x); f[1] = bfhi(u.x);
    f[2] = bflo(u.y); f[3] = bfhi(u.y);
    f[4] = bflo(u.z); f[5] = bfhi(u.z);
    f[6] = bflo(u.w); f[7] = bfhi(u.w);
}

// ---------------- prep: bf16 converts (blocks [0,cvtBlocks)) + edge count ----
__global__ __launch_bounds__(256) void prep(const float* __restrict__ x, ushort* __restrict__ xb, int nx4,
                                            const float* __restrict__ w1, ushort* __restrict__ w1b, int nw14,
                                            const float* __restrict__ w2, ushort* __restrict__ w2b, int nw24,
                                            int cvtBlocks,
                                            const int* __restrict__ edst, int* __restrict__ cnt, int E) {
    int blk = blockIdx.x;
    if (blk < cvtBlocks) {
        int j = blk * 256 + threadIdx.x;
        const float* src; ushort* dst;
        if (j < nx4) { src = x; dst = xb; }
        else {
            j -= nx4;
            if (j < nw14) { src = w1; dst = w1b; }
            else {
                j -= nw14;
                if (j >= nw24) return;
                src = w2; dst = w2b;
            }
        }
        float4 v = ((const float4*)src)[j];
        uint2 o;
        o.x = pack2(v.x, v.y);
        o.y = pack2(v.z, v.w);
        ((uint2*)dst)[j] = o;
    } else {
        int e = (blk - cvtBlocks) * 256 + threadIdx.x;
        if (e < E) atomicAdd(&cnt[edst[e]], 1);
    }
}

// ---------------- GEMM body: C[M,N]=A[M,K]*B[N,K]^T, software-pipelined ------
__device__ __forceinline__ void gemm_body(ushort* As, ushort* Bs,
                                          const ushort* __restrict__ A,
                                          const ushort* __restrict__ B,
                                          ushort* __restrict__ C,
                                          int M, int N, int K, int bx, int by,
                                          const float* __restrict__ att_s,
                                          const float* __restrict__ att_d,
                                          float* __restrict__ sout,
                                          float* __restrict__ dout, int H) {
    int t = threadIdx.x;
    int wave = t >> 6, lane = t & 63;
    int quad = lane >> 4, l16 = lane & 15;
    int m0 = bx * 128, n0 = by * 128;
    int wm = (wave & 1) * 64;
    int wn = (wave >> 1) * 64;
    int srow = t >> 1;
    int sseg = (t & 1) * 16;          // element offset (16 bf16 = 32 B)
    int growA = m0 + srow;
    bool okA = growA < M;
    f32x4 acc[4][4] = {};             // [mi][nj]
    uint4 av0, av1, bv0, bv1;
    {   // preload chunk 0
        if (okA) {
            const uint4* gp = (const uint4*)(A + (size_t)growA * K + sseg);
            av0 = gp[0]; av1 = gp[1];
        } else { av0 = make_uint4(0, 0, 0, 0); av1 = av0; }
        const uint4* gq = (const uint4*)(B + (size_t)(n0 + srow) * K + sseg);
        bv0 = gq[0]; bv1 = gq[1];
    }
    for (int k0 = 0; k0 < K; k0 += 32) {
        __syncthreads();   // previous chunk's LDS readers done
        *(uint4*)&As[srow * LDSB + sseg]     = av0;
        *(uint4*)&As[srow * LDSB + sseg + 8] = av1;
        *(uint4*)&Bs[srow * LDSB + sseg]     = bv0;
        *(uint4*)&Bs[srow * LDSB + sseg + 8] = bv1;
        __syncthreads();
        int k1 = k0 + 32;
        if (k1 < K) {   // issue next-chunk loads BEFORE compute (overlap)
            if (okA) {
                const uint4* gp = (const uint4*)(A + (size_t)growA * K + k1 + sseg);
                av0 = gp[0]; av1 = gp[1];
            } else { av0 = make_uint4(0, 0, 0, 0); av1 = av0; }
            const uint4* gq = (const uint4*)(B + (size_t)(n0 + srow) * K + k1 + sseg);
            bv0 = gq[0]; bv1 = gq[1];
        }
        bf16x8 af[4], bf[4];
#pragma unroll
        for (int i = 0; i < 4; ++i)
            af[i] = *(const bf16x8*)&As[(wm + i * 16 + l16) * LDSB + quad * 8];
#pragma unroll
        for (int j = 0; j < 4; ++j)
            bf[j] = *(const bf16x8*)&Bs[(wn + j * 16 + l16) * LDSB + quad * 8];
#pragma unroll
        for (int i = 0; i < 4; ++i)
#pragma unroll
            for (int j = 0; j < 4; ++j)
                acc[i][j] = __builtin_amdgcn_mfma_f32_16x16x32_bf16(
                    af[i], bf[j], acc[i][j], 0, 0, 0);
    }
    // epilogue: C/D layout col=lane&15, row=quad*4+reg
#pragma unroll
    for (int i = 0; i < 4; ++i) {
#pragma unroll
        for (int r = 0; r < 4; ++r) {
            int grow = m0 + wm + i * 16 + quad * 4 + r;
            if (grow < M) {
#pragma unroll
                for (int j = 0; j < 4; ++j) {
                    int gcol = n0 + wn + j * 16 + l16;
                    C[(size_t)grow * N + gcol] = f2bf(acc[i][j][r]);
                }
            }
        }
    }
    // fused score epilogue
    float as[4], adw[4];
#pragma unroll
    for (int j = 0; j < 4; ++j) {
        int col = n0 + wn + j * 16 + l16;   // flat index into att (H*C = N)
        as[j]  = att_s[col];
        adw[j] = att_d[col];
    }
    int head = (H == 8) ? ((n0 + wn) >> 6) : 0;
#pragma unroll
    for (int i = 0; i < 4; ++i) {
#pragma unroll
        for (int r = 0; r < 4; ++r) {
            float ps = acc[i][0][r] * as[0] + acc[i][1][r] * as[1] +
                       acc[i][2][r] * as[2] + acc[i][3][r] * as[3];
            float pd = acc[i][0][r] * adw[0] + acc[i][1][r] * adw[1] +
                       acc[i][2][r] * adw[2] + acc[i][3][r] * adw[3];
#pragma unroll
            for (int off = 1; off < 16; off <<= 1) {
                ps += __shfl_xor(ps, off);
                pd += __shfl_xor(pd, off);
            }
            int grow = m0 + wm + i * 16 + quad * 4 + r;
            if (l16 == 0 && grow < M) {
                if (H == 1) {
                    atomicAdd(&sout[grow], ps);
                    atomicAdd(&dout[grow], pd);
                } else {
                    sout[grow * 8 + head] = ps;
                    dout[grow * 8 + head] = pd;
                }
            }
        }
    }
}

// ---------------- fused gemm1 + fill_edges (independent work, block-split) ----
__global__ __launch_bounds__(256) void g1f(const ushort* __restrict__ A,
                                           const ushort* __restrict__ B,
                                           ushort* __restrict__ C,
                                           int M, int N, int K,
                                           const float* __restrict__ att_s,
                                           const float* __restrict__ att_d,
                                           float* __restrict__ sout,
                                           float* __restrict__ dout, int H,
                                           int gemmBlocks, int nby,
                                           const int* __restrict__ esrc,
                                           const int* __restrict__ edst,
                                           int* __restrict__ cursor,
                                           int* __restrict__ srcs, int E) {
    __shared__ ushort As[128 * LDSB];
    __shared__ ushort Bs[128 * LDSB];
    int blk = blockIdx.x;
    if (blk < gemmBlocks) {
        gemm_body(As, Bs, A, B, C, M, N, K, blk / nby, blk % nby,
                  att_s, att_d, sout, dout, H);
    } else {
        int e = (blk - gemmBlocks) * 256 + threadIdx.x;
        if (e < E) {
            int pos = atomicAdd(&cursor[edst[e]], 1);
            srcs[pos] = esrc[e];
        }
    }
}

// ---------------- plain GEMM kernel (layer 2) ----------------
__global__ __launch_bounds__(256) void gemm_k(const ushort* __restrict__ A,
                                              const ushort* __restrict__ B,
                                              ushort* __restrict__ C,
                                              int M, int N, int K,
                                              const float* __restrict__ att_s,
                                              const float* __restrict__ att_d,
                                              float* __restrict__ sout,
                                              float* __restrict__ dout, int H,
                                              int nby) {
    __shared__ ushort As[128 * LDSB];
    __shared__ ushort Bs[128 * LDSB];
    gemm_body(As, Bs, A, B, C, M, N, K, blockIdx.x / nby, blockIdx.x % nby,
              att_s, att_d, sout, dout, H);
}

// ---------------- CSR scan + out prefill (out = b_out per graph) ----------
__global__ __launch_bounds__(1024) void scan_offsets(const int* cnt, int* row_start,
                                                     int* cursor, int N,
                                                     const float* __restrict__ b_out,
                                                     float* __restrict__ out) {
    __shared__ int sm[1024];
    int t = threadIdx.x;
    if (t < 512) out[t] = b_out[t & 1];
    int per = (N + 1023) / 1024;
    int beg = t * per;
    int end = beg + per; if (end > N) end = N;
    int sum = 0;
    for (int i = beg; i < end; ++i) sum += cnt[i];
    sm[t] = sum;
    __syncthreads();
    for (int off = 1; off < 1024; off <<= 1) {
        int add = (t >= off) ? sm[t - off] : 0;
        __syncthreads();
        sm[t] += add;
        __syncthreads();
    }
    int run = sm[t] - sum;
    for (int i = beg; i < end; ++i) {
        int c = cnt[i];
        row_start[i] = run;
        cursor[i] = run;
        run += c;
    }
    if (t == 1023) row_start[N] = run;
}

// -------- Layer-1 softmax-aggregate (R4 structure: 4-deep unroll + tail) -----
__global__ __launch_bounds__(256) void agg1(const ushort* __restrict__ h1,
                                            const float* __restrict__ a1s,
                                            const float* __restrict__ a1d,
                                            const int* __restrict__ row_start,
                                            const int* __restrict__ srcs,
                                            const float* __restrict__ b1,
                                            ushort* __restrict__ r1, int N) {
    int node = blockIdx.x * 4 + (threadIdx.x >> 6);
    if (node >= N) return;
    int lane = threadIdx.x & 63;
    int head = lane >> 3;
    int f0 = lane * 8;
    int pbeg = row_start[node], pend = row_start[node + 1];
    float ad = a1d[node * 8 + head];
    float es = a1s[node * 8 + head] + ad;
    es = es > 0.f ? es : NEG_SLOPE * es;
    float ex_self = __expf(es);
    float den = ex_self;
    float q[8];
    unpack8(*(const uint4*)(h1 + (size_t)node * 512 + f0), q);
    float acc[8];
#pragma unroll
    for (int j = 0; j < 8; ++j) acc[j] = ex_self * q[j];
    int p = pbeg;
    for (; p + 4 <= pend; p += 4) {
        int s0 = srcs[p + 0];
        int s1 = srcs[p + 1];
        int s2 = srcs[p + 2];
        int s3 = srcs[p + 3];
        uint4 u0 = *(const uint4*)(h1 + (size_t)s0 * 512 + f0);
        uint4 u1 = *(const uint4*)(h1 + (size_t)s1 * 512 + f0);
        uint4 u2 = *(const uint4*)(h1 + (size_t)s2 * 512 + f0);
        uint4 u3 = *(const uint4*)(h1 + (size_t)s3 * 512 + f0);
        float as0 = a1s[s0 * 8 + head];
        float as1 = a1s[s1 * 8 + head];
        float as2 = a1s[s2 * 8 + head];
        float as3 = a1s[s3 * 8 + head];
        float e0 = as0 + ad; e0 = e0 > 0.f ? e0 : NEG_SLOPE * e0;
        float e1 = as1 + ad; e1 = e1 > 0.f ? e1 : NEG_SLOPE * e1;
        float e2 = as2 + ad; e2 = e2 > 0.f ? e2 : NEG_SLOPE * e2;
        float e3 = as3 + ad; e3 = e3 > 0.f ? e3 : NEG_SLOPE * e3;
        float x0 = __expf(e0), x1 = __expf(e1), x2 = __expf(e2), x3 = __expf(e3);
        den += (x0 + x1) + (x2 + x3);
        float v[8];
        unpack8(u0, v);
#pragma unroll
        for (int j = 0; j < 8; ++j) acc[j] += x0 * v[j];
        unpack8(u1, v);
#pragma unroll
        for (int j = 0; j < 8; ++j) acc[j] += x1 * v[j];
        unpack8(u2, v);
#pragma unroll
        for (int j = 0; j < 8; ++j) acc[j] += x2 * v[j];
        unpack8(u3, v);
#pragma unroll
        for (int j = 0; j < 8; ++j) acc[j] += x3 * v[j];
    }
    for (; p < pend; ++p) {
        int s = srcs[p];
        float e = a1s[s * 8 + head] + ad;
        e = e > 0.f ? e : NEG_SLOPE * e;
        float ex = __expf(e);
        den += ex;
        float v[8];
        unpack8(*(const uint4*)(h1 + (size_t)s * 512 + f0), v);
#pragma unroll
        for (int j = 0; j < 8; ++j) acc[j] += ex * v[j];
    }
    float rden = 1.0f / (den + 1e-16f);
    const float4* bp = (const float4*)(b1 + f0);
    float4 b0 = bp[0], b1v = bp[1];
    float o[8];
    o[0] = fmaxf(acc[0] * rden + b0.x, 0.f);
    o[1] = fmaxf(acc[1] * rden + b0.y, 0.f);
    o[2] = fmaxf(acc[2] * rden + b0.z, 0.f);
    o[3] = fmaxf(acc[3] * rden + b0.w, 0.f);
    o[4] = fmaxf(acc[4] * rden + b1v.x, 0.f);
    o[5] = fmaxf(acc[5] * rden + b1v.y, 0.f);
    o[6] = fmaxf(acc[6] * rden + b1v.z, 0.f);
    o[7] = fmaxf(acc[7] * rden + b1v.w, 0.f);
    uint4 ov;
    ov.x = pack2(o[0], o[1]); ov.y = pack2(o[2], o[3]);
    ov.z = pack2(o[4], o[5]); ov.w = pack2(o[6], o[7]);
    *(uint4*)(r1 + (size_t)node * 512 + f0) = ov;
}

// -------- Layer-2 aggregate + pooling + output GEMM (R13 + 2-stage pipeline) --
// 4 nodes / 64-lane wave (16-lane groups), uint4 (8 feats) per lane.
// Explicit software pipeline: batch i+1's srcs/rows/scores issued BEFORE
// batch i's exp/FMA consume, hiding the loop-carried gather chain.
__global__ __launch_bounds__(256) void agg2out(const ushort* __restrict__ h2,
                                               const float* __restrict__ a2s,
                                               const float* __restrict__ a2d,
                                               const int* __restrict__ row_start,
                                               const int* __restrict__ srcs,
                                               const float* __restrict__ b2,
                                               const int* __restrict__ batch,
                                               const float* __restrict__ w_attn,
                                               const float* __restrict__ b_attn,
                                               const float* __restrict__ w_mask,
                                               const float* __restrict__ b_mask,
                                               const float* __restrict__ W_out,
                                               float* __restrict__ out, int N) {
    int node = blockIdx.x * 16 + (threadIdx.x >> 4);
    if (node >= N) return;
    int sub = threadIdx.x & 15;
    int f0 = sub * 8;                          // 8 feats (16B) per lane
    int pbeg = row_start[node], pend = row_start[node + 1];
    float ad = a2d[node];
    float es = a2s[node] + ad;
    es = es > 0.f ? es : NEG_SLOPE * es;
    float ex_self = __expf(es);
    float den = ex_self;
    float q[8];
    unpack8(*(const uint4*)(h2 + (size_t)node * 128 + f0), q);
    float acc[8];
#pragma unroll
    for (int j = 0; j < 8; ++j) acc[j] = ex_self * q[j];

#define A2_CONSUME(U0, U1, U2, U3, S0, S1, S2, S3)                          \
    {                                                                        \
        float e0 = S0 + ad; e0 = e0 > 0.f ? e0 : NEG_SLOPE * e0;             \
        float e1 = S1 + ad; e1 = e1 > 0.f ? e1 : NEG_SLOPE * e1;             \
        float e2 = S2 + ad; e2 = e2 > 0.f ? e2 : NEG_SLOPE * e2;             \
        float e3 = S3 + ad; e3 = e3 > 0.f ? e3 : NEG_SLOPE * e3;             \
        float x0 = __expf(e0), x1 = __expf(e1), x2 = __expf(e2),             \
              x3 = __expf(e3);                                               \
        den += (x0 + x1) + (x2 + x3);                                        \
        float v[8];                                                          \
        unpack8(U0, v);                                                      \
        _Pragma("unroll") for (int j = 0; j < 8; ++j) acc[j] += x0 * v[j];   \
        unpack8(U1, v);                                                      \
        _Pragma("unroll") for (int j = 0; j < 8; ++j) acc[j] += x1 * v[j];   \
        unpack8(U2, v);                                                      \
        _Pragma("unroll") for (int j = 0; j < 8; ++j) acc[j] += x2 * v[j];   \
        unpack8(U3, v);                                                      \
        _Pragma("unroll") for (int j = 0; j < 8; ++j) acc[j] += x3 * v[j];   \
    }

    int p = pbeg;
    int pendF = pbeg + ((pend - pbeg) & ~3);
    if (p < pendF) {
        // prologue: batch 0
        int s0 = srcs[p + 0], s1 = srcs[p + 1], s2 = srcs[p + 2], s3 = srcs[p + 3];
        uint4 u0 = *(const uint4*)(h2 + (size_t)s0 * 128 + f0);
        uint4 u1 = *(const uint4*)(h2 + (size_t)s1 * 128 + f0);
        uint4 u2 = *(const uint4*)(h2 + (size_t)s2 * 128 + f0);
        uint4 u3 = *(const uint4*)(h2 + (size_t)s3 * 128 + f0);
        float as0 = a2s[s0], as1 = a2s[s1], as2 = a2s[s2], as3 = a2s[s3];
        for (p += 4; p < pendF; p += 4) {
            // issue batch i+1 loads BEFORE consuming batch i
            int t0 = srcs[p + 0], t1 = srcs[p + 1], t2 = srcs[p + 2], t3 = srcs[p + 3];
            uint4 v0 = *(const uint4*)(h2 + (size_t)t0 * 128 + f0);
            uint4 v1 = *(const uint4*)(h2 + (size_t)t1 * 128 + f0);
            uint4 v2 = *(const uint4*)(h2 + (size_t)t2 * 128 + f0);
            uint4 v3 = *(const uint4*)(h2 + (size_t)t3 * 128 + f0);
            float bs0 = a2s[t0], bs1 = a2s[t1], bs2 = a2s[t2], bs3 = a2s[t3];
            A2_CONSUME(u0, u1, u2, u3, as0, as1, as2, as3);
            u0 = v0; u1 = v1; u2 = v2; u3 = v3;
            as0 = bs0; as1 = bs1; as2 = bs2; as3 = bs3;
        }
        A2_CONSUME(u0, u1, u2, u3, as0, as1, as2, as3);
    }
    for (; p < pend; ++p) {
        int s = srcs[p];
        uint4 u = *(const uint4*)(h2 + (size_t)s * 128 + f0);
        float e = a2s[s] + ad;
        e = e > 0.f ? e : NEG_SLOPE * e;
        float ex = __expf(e);
        den += ex;
        float v[8];
        unpack8(u, v);
#pragma unroll
        for (int j = 0; j < 8; ++j) acc[j] += ex * v[j];
    }
#undef A2_CONSUME

    float rden = 1.0f / (den + 1e-16f);
    const float4* bp = (const float4*)(b2 + f0);
    float4 b0 = bp[0], b1v = bp[1];
    float o[8];
    o[0] = fmaxf(acc[0] * rden + b0.x, 0.f);
    o[1] = fmaxf(acc[1] * rden + b0.y, 0.f);
    o[2] = fmaxf(acc[2] * rden + b0.z, 0.f);
    o[3] = fmaxf(acc[3] * rden + b0.w, 0.f);
    o[4] = fmaxf(acc[4] * rden + b1v.x, 0.f);
    o[5] = fmaxf(acc[5] * rden + b1v.y, 0.f);
    o[6] = fmaxf(acc[6] * rden + b1v.z, 0.f);
    o[7] = fmaxf(acc[7] * rden + b1v.w, 0.f);
    // ---- fused pooling + output projection ----
    const float4* wap = (const float4*)(w_attn + f0);
    const float4* wmp = (const float4*)(w_mask + f0);
    const float4* w0p = (const float4*)(W_out + f0);
    const float4* w1p = (const float4*)(W_out + 128 + f0);
    float4 wa0 = wap[0], wa1 = wap[1];
    float4 wm0 = wmp[0], wm1 = wmp[1];
    float4 wo0 = w0p[0], wo1 = w0p[1];
    float4 wp0 = w1p[0], wp1 = w1p[1];
    float pa = o[0] * wa0.x + o[1] * wa0.y + o[2] * wa0.z + o[3] * wa0.w +
               o[4] * wa1.x + o[5] * wa1.y + o[6] * wa1.z + o[7] * wa1.w;
    float pm = o[0] * wm0.x + o[1] * wm0.y + o[2] * wm0.z + o[3] * wm0.w +
               o[4] * wm1.x + o[5] * wm1.y + o[6] * wm1.z + o[7] * wm1.w;
    float d0 = o[0] * wo0.x + o[1] * wo0.y + o[2] * wo0.z + o[3] * wo0.w +
               o[4] * wo1.x + o[5] * wo1.y + o[6] * wo1.z + o[7] * wo1.w;
    float d1 = o[0] * wp0.x + o[1] * wp0.y + o[2] * wp0.z + o[3] * wp0.w +
               o[4] * wp1.x + o[5] * wp1.y + o[6] * wp1.z + o[7] * wp1.w;
#pragma unroll
    for (int off = 1; off < 16; off <<= 1) {
        pa += __shfl_xor(pa, off);
        pm += __shfl_xor(pm, off);
        d0 += __shfl_xor(d0, off);
        d1 += __shfl_xor(d1, off);
    }
    if (sub == 0) {
        float attn = pa + b_attn[0];
        float mask = 1.0f / (1.0f + __expf(-(pm + b_mask[0])));
        float w = attn * mask;
        int g = batch[node];
        atomicAdd(&out[g * 2 + 0], w * d0);
        atomicAdd(&out[g * 2 + 1], w * d1);
    }
}

extern "C" void kernel_launch(void* const* d_in, const int* in_sizes, int n_in,
                              void* d_out, int out_size, void* d_ws, size_t ws_size,
                              hipStream_t stream) {
    const float* x        = (const float*)d_in[0];
    const int* edge_index = (const int*)d_in[1];
    const int* batch      = (const int*)d_in[2];
    const float* W1       = (const float*)d_in[3];
    const float* att_src1 = (const float*)d_in[4];
    const float* att_dst1 = (const float*)d_in[5];
    const float* b1       = (const float*)d_in[6];
    const float* W2       = (const float*)d_in[7];
    const float* att_src2 = (const float*)d_in[8];
    const float* att_dst2 = (const float*)d_in[9];
    const float* b2       = (const float*)d_in[10];
    const float* w_attn   = (const float*)d_in[11];
    const float* b_attn   = (const float*)d_in[12];
    const float* w_mask   = (const float*)d_in[13];
    const float* b_mask   = (const float*)d_in[14];
    const float* W_out    = (const float*)d_in[15];
    const float* b_out    = (const float*)d_in[16];
    float* out = (float*)d_out;

    int N = in_sizes[0] / 128;
    int E = in_sizes[1] / 2;
    const int* esrc = edge_index;
    const int* edst = edge_index + E;

    char* ws = (char*)d_ws;
    size_t off = 0;
    auto alloc = [&](size_t bytes) {
        void* p = ws + off;
        off = (off + bytes + 255) & ~(size_t)255;
        return p;
    };
    ushort* h1       = (ushort*)alloc((size_t)N * 512 * 2);   // bf16
    ushort* r1       = (ushort*)alloc((size_t)N * 512 * 2);   // bf16
    ushort* h2       = (ushort*)alloc((size_t)N * 128 * 2);   // bf16
    ushort* xb       = (ushort*)alloc((size_t)N * 128 * 2);   // bf16 x
    ushort* w1b      = (ushort*)alloc((size_t)512 * 128 * 2);
    ushort* w2b      = (ushort*)alloc((size_t)128 * 512 * 2);
    float*  a1s      = (float*)alloc((size_t)N * 8 * 4);
    float*  a1d      = (float*)alloc((size_t)N * 8 * 4);
    int*    row_start= (int*)alloc((size_t)(N + 1) * 4);
    int*    srcs     = (int*)alloc((size_t)E * 4);
    // zero-init region: cursor, a2s, a2d (contiguous, one memset)
    int*    cursor   = (int*)alloc((size_t)N * 4);
    float*  a2s      = (float*)alloc((size_t)N * 4);
    float*  a2d      = (float*)alloc((size_t)N * 4);
    size_t zspan = (size_t)((char*)(a2d + N) - (char*)cursor);
    hipMemsetAsync(cursor, 0, zspan, stream);

    dim3 b256(256);
    // prep: converts + edge count in one launch
    int nx4 = N * 128 / 4;
    int nw4 = 512 * 128 / 4;
    int cvtBlocks = (nx4 + 2 * nw4 + 255) / 256;
    int cntBlocks = (E + 255) / 256;
    prep<<<cvtBlocks + cntBlocks, b256, 0, stream>>>(x, xb, nx4, W1, w1b, nw4,
                                                     W2, w2b, nw4, cvtBlocks,
                                                     edst, cursor, E);
    scan_offsets<<<1, 1024, 0, stream>>>(cursor, row_start, cursor, N, b_out, out);
    // gemm1 (fused scores H=8) + fill_edges in one launch
    int g1Blocks = ((N + 127) / 128) * 4;
    g1f<<<g1Blocks + cntBlocks, b256, 0, stream>>>(xb, w1b, h1, N, 512, 128,
                                                   att_src1, att_dst1, a1s, a1d, 8,
                                                   g1Blocks, 4,
                                                   esrc, edst, cursor, srcs, E);
    agg1<<<(N + 3) / 4, b256, 0, stream>>>(h1, a1s, a1d, row_start, srcs, b1, r1, N);
    // layer 2 gemm (fused scores H=1, atomics into zeroed a2s/a2d)
    gemm_k<<<(N + 127) / 128, b256, 0, stream>>>(r1, w2b, h2, N, 128, 512,
                                                 att_src2, att_dst2, a2s, a2d, 1, 1);
    // layer 2 aggregate + pooling + output projection fused
    agg2out<<<(N + 15) / 16, b256, 0, stream>>>(h2, a2s, a2d, row_start, srcs, b2,
                                                batch, w_attn, b_attn, w_mask, b_mask,
                                                W_out, out, N);
}